// Round 3
// baseline (360.916 us; speedup 1.0000x reference)
//
#include <hip/hip_runtime.h>
#include <hip/hip_bf16.h>

typedef __hip_bfloat16 bf16;
typedef unsigned short u16;
typedef float f32x2 __attribute__((ext_vector_type(2)));

#define NC 8192
#define NF 32768
#define KNN 16
#define FMAXV 3.402823466e+38f

__device__ __forceinline__ float bfbits2f(u16 u){
  union { unsigned u; float f; } x; x.u = ((unsigned)u) << 16; return x.f;
}
__device__ __forceinline__ float asfloat(unsigned u){
  union { unsigned u; float f; } x; x.u = u; return x.f;
}
// packed fp32 fma: d = a*b + c on both halves (IEEE fma per half, bit-exact vs fmaf)
__device__ __forceinline__ f32x2 pk_fma(f32x2 a, f32x2 b, f32x2 c){
  f32x2 d;
  asm("v_pk_fma_f32 %0, %1, %2, %3" : "=v"(d) : "v"(a), "v"(b), "v"(c));
  return d;
}

// ---------- k_prep: paired-candidate pos layout + MLP weight swizzles (grid 64 x 256 = 16384) ----------
// posP[2q]   = (x_{2q}, x_{2q+1}, y_{2q}, y_{2q+1})
// posP[2q+1] = (z_{2q}, z_{2q+1}, w_{2q}, w_{2q+1})   w = |d|^2/2
__global__ __launch_bounds__(256) void k_prep(const float* __restrict__ dpos,
                                              const float* __restrict__ W1,
                                              const float* __restrict__ W2,
                                              float4* __restrict__ posP,
                                              float4* __restrict__ W1eSa,
                                              float4* __restrict__ W1eSb,
                                              float4* __restrict__ W2Sa,
                                              float4* __restrict__ W2Sb){
  int g = blockIdx.x * 256 + threadIdx.x;
  if (g < 4096){
    const float2* dp2 = (const float2*)(dpos + (size_t)g * 6);
    float2 a = dp2[0], b = dp2[1], c = dp2[2];
    float x0 = a.x, y0 = a.y, z0 = b.x;
    float x1 = b.y, y1 = c.x, z1 = c.y;
    float dd0 = __fadd_rn(__fadd_rn(__fmul_rn(x0,x0), __fmul_rn(y0,y0)), __fmul_rn(z0,z0));
    float dd1 = __fadd_rn(__fadd_rn(__fmul_rn(x1,x1), __fmul_rn(y1,y1)), __fmul_rn(z1,z1));
    posP[g * 2]     = make_float4(x0, x1, y0, y1);
    posP[g * 2 + 1] = make_float4(z0, z1, dd0 * 0.5f, dd1 * 0.5f);
  } else if (g >= 8192 && g < 10240){
    int f = g - 8192; int c4 = f >> 6, jg = f & 63;
    W1eSa[f] = ((const float4*)(W1 + (size_t)(2 * jg) * 384 + 256))[c4];
  } else if (g >= 10240 && g < 12288){
    int f = g - 10240; int c4 = f >> 6, jg = f & 63;
    W1eSb[f] = ((const float4*)(W1 + (size_t)(2 * jg + 1) * 384 + 256))[c4];
  } else if (g >= 12288 && g < 14336){
    int f = g - 12288; int c4 = f >> 6, jg = f & 63;
    W2Sa[f] = ((const float4*)(W2 + (size_t)(2 * jg) * 128))[c4];
  } else if (g >= 14336){
    int f = g - 14336; int c4 = f >> 6, jg = f & 63;
    W2Sb[f] = ((const float4*)(W2 + (size_t)(2 * jg + 1) * 128))[c4];
  }
}

// ---------- k_wprod: weight-product fold, 4-way K-split for TLP (grid 257*4 = 1028) ----------
// block B: csel = B>>2 selects output column; tch = B&3 selects the 64-wide output chunk.
// threads: o = (t&63)+tch*64 (output), q = t>>6 (K-part, 64 j each). LDS reduce of 4 partials.
__global__ __launch_bounds__(256) void k_wprod(const float* __restrict__ Wk,
                                               const float* __restrict__ Wv,
                                               const float* __restrict__ Wq,
                                               const float* __restrict__ W1,
                                               const float* __restrict__ bk,
                                               const float* __restrict__ bv,
                                               const float* __restrict__ bq,
                                               float* __restrict__ WkqS,
                                               float* __restrict__ WvuS,
                                               float* __restrict__ bkq,
                                               float* __restrict__ bvu,
                                               float* __restrict__ wbq,
                                               float* __restrict__ sbq){
  __shared__ float partial[256];
  __shared__ float red[256];
  int B = blockIdx.x, t = threadIdx.x;
  int csel = B >> 2, tch = B & 3;
  int o = (t & 63) + tch * 64;
  int q = t >> 6;
  int j0 = q * 64;
  if (csel < 128){
    int c = csel;
    float acc = 0.f;
    for (int j = j0; j < j0 + 64; ++j)
      acc = fmaf(Wk[(size_t)j * 256 + o], Wq[(size_t)j * 128 + c], acc);
    partial[t] = acc;
    if (tch == 0) red[t] = bk[t] * Wq[(size_t)t * 128 + c];
    __syncthreads();
    if (t < 64){
      float a = partial[t] + partial[t + 64] + partial[t + 128] + partial[t + 192];
      WkqS[(size_t)((o >> 2) * 128 + c) * 4 + (o & 3)] = a;
    }
    if (tch == 0){
      for (int s = 128; s > 0; s >>= 1){ if (t < s) red[t] += red[t + s]; __syncthreads(); }
      if (t == 0) bkq[c] = red[0];
    }
  } else if (csel < 256){
    int h = csel - 128;
    float acc = 0.f;
    for (int j = j0; j < j0 + 64; ++j)
      acc = fmaf(Wv[(size_t)j * 256 + o], W1[(size_t)h * 384 + j], acc);
    partial[t] = acc;
    if (tch == 0) red[t] = bv[t] * W1[(size_t)h * 384 + t];
    __syncthreads();
    if (t < 64){
      float a = partial[t] + partial[t + 64] + partial[t + 128] + partial[t + 192];
      WvuS[(size_t)((o >> 2) * 128 + h) * 4 + (o & 3)] = a;
    }
    if (tch == 0){
      for (int s = 128; s > 0; s >>= 1){ if (t < s) red[t] += red[t + s]; __syncthreads(); }
      if (t == 0) bvu[h] = red[0];
    }
  } else {
    float acc = 0.f;
    for (int j = j0; j < j0 + 64; ++j)
      acc = fmaf(Wk[(size_t)j * 256 + o], bq[j], acc);
    partial[t] = acc;
    if (tch == 0) red[t] = bk[t] * bq[t];
    __syncthreads();
    if (t < 64){
      float a = partial[t] + partial[t + 64] + partial[t + 128] + partial[t + 192];
      wbq[o] = a;
    }
    if (tch == 0){
      for (int s = 128; s > 0; s >>= 1){ if (t < s) red[t] += red[t + s]; __syncthreads(); }
      if (t == 0) sbq[0] = red[0];
    }
  }
}

// ---------- k_dec: Zd = df@Wkq + bkq, Ud = df@Wvu + bvu, bqK = df@wbq + sbq (8 rows/block) ----------
__global__ __launch_bounds__(256) void k_dec(const float* __restrict__ df,
                                             const float4* __restrict__ WkqS,
                                             const float4* __restrict__ WvuS,
                                             const float* __restrict__ bkq,
                                             const float* __restrict__ bvu,
                                             const float* __restrict__ wbq,
                                             const float* __restrict__ sbq,
                                             bf16* __restrict__ Zd, bf16* __restrict__ Ud,
                                             float* __restrict__ bqK){
  __shared__ float part[8][32];
  int t = threadIdx.x;
  int g0 = blockIdx.x * 8;
  int half = __builtin_amdgcn_readfirstlane(t >> 7);
  int c = t & 127;
  const float4* W = half ? WvuS : WkqS;
  float acc[8];
  #pragma unroll
  for (int p = 0; p < 8; ++p) acc[p] = 0.f;
  for (int j4 = 0; j4 < 64; ++j4){
    float4 w = W[j4 * 128 + c];
    #pragma unroll
    for (int p = 0; p < 8; ++p){
      float4 a = ((const float4*)(df + (size_t)(g0 + p) * 256))[j4];
      acc[p] += w.x*a.x + w.y*a.y + w.z*a.z + w.w*a.w;
    }
  }
  float bias = half ? bvu[c] : bkq[c];
  bf16* dst = half ? Ud : Zd;
  #pragma unroll
  for (int p = 0; p < 8; ++p)
    dst[(size_t)(g0 + p) * 128 + c] = __float2bfloat16(acc[p] + bias);
  {
    int r = t >> 5, seg = t & 31;
    float s = 0.f;
    const float* dr = df + (size_t)(g0 + r) * 256 + seg * 8;
    const float* wq = wbq + seg * 8;
    #pragma unroll
    for (int e = 0; e < 8; ++e) s = fmaf(dr[e], wq[e], s);
    part[r][seg] = s;
  }
  __syncthreads();
  if (t < 8){
    float s = sbq[0];
    #pragma unroll
    for (int seg = 0; seg < 32; ++seg) s += part[t][seg];
    bqK[g0 + t] = s;
  }
}

// ---------- fused KNN + attention, wave-autonomous: 128-thr blocks, each wave owns 8 points ----------
// Each wave scans ALL 8192 candidates for its 8 points (keeps the 8-point read amortization).
// tau0[p] = 17th smallest of the wave's own 64 lane-minima (sound: 64 disjoint 128-candidate bins
// -> >=17 distinct candidates <= tau0). Pass B appends via ballot+prefix popcount (no LDS atomics).
// One barrier total; waves share nothing.
__global__ __launch_bounds__(128) void k_attn(const float* __restrict__ epos,
                                              const float4* __restrict__ posP,
                                              const float* __restrict__ ef,
                                              const bf16* __restrict__ Zd,
                                              const bf16* __restrict__ Ud,
                                              const float* __restrict__ bqK,
                                              bf16* __restrict__ hagg){
  __shared__ float lval[2][8][64];
  __shared__ int   lidx[2][8][64];
  __shared__ int   cntL[2][8];

  int t = threadIdx.x, lane = t & 63, w = t >> 6;
  int n0 = blockIdx.x * 16 + w * 8;

  f32x2 nex2[8], ney2[8], nez2[8];
  #pragma unroll
  for (int p = 0; p < 8; ++p){
    float nx = -epos[(n0 + p) * 3 + 0];
    float ny = -epos[(n0 + p) * 3 + 1];
    float nz = -epos[(n0 + p) * 3 + 2];
    nex2[p].x = nx; nex2[p].y = nx;
    ney2[p].x = ny; ney2[p].y = ny;
    nez2[p].x = nz; nez2[p].y = nz;
  }

  // PASS A: per-lane minima over all 4096 candidate pairs (3 pk_fma + 2 min per point)
  f32x2 vmin2[8];
  #pragma unroll
  for (int p = 0; p < 8; ++p){ vmin2[p].x = FMAXV; vmin2[p].y = FMAXV; }
  #pragma unroll 2
  for (int s = 0; s < 64; ++s){
    int q2 = (s * 64 + lane) * 2;
    float4 XY = posP[q2], ZW = posP[q2 + 1];
    f32x2 X = {XY.x, XY.y}, Y = {XY.z, XY.w}, Z = {ZW.x, ZW.y}, W = {ZW.z, ZW.w};
    #pragma unroll
    for (int p = 0; p < 8; ++p){
      f32x2 v2 = pk_fma(nex2[p], X, W);
      v2 = pk_fma(ney2[p], Y, v2);
      v2 = pk_fma(nez2[p], Z, v2);
      vmin2[p].x = fminf(vmin2[p].x, v2.x);
      vmin2[p].y = fminf(vmin2[p].y, v2.y);
    }
  }
  float vmin[8];
  #pragma unroll
  for (int p = 0; p < 8; ++p) vmin[p] = fminf(vmin2[p].x, vmin2[p].y);

  // full bitonic sort of 64 lane-minima (8 points at once); lane L -> (L+1)-th smallest
  #pragma unroll
  for (int k = 2; k <= 64; k <<= 1){
    #pragma unroll
    for (int j = k >> 1; j > 0; j >>= 1){
      bool keepmin = ((lane & j) == 0) == ((lane & k) == 0);
      #pragma unroll
      for (int p = 0; p < 8; ++p){
        float pv = __shfl_xor(vmin[p], j);
        vmin[p] = keepmin ? fminf(vmin[p], pv) : fmaxf(vmin[p], pv);
      }
    }
  }
  float tau0[8];
  #pragma unroll
  for (int p = 0; p < 8; ++p) tau0[p] = __shfl(vmin[p], 16);   // 17th smallest

  // PASS B: filtered append via ballot + prefix popcount (identical packed val expression)
  unsigned long long lmlt = (1ull << lane) - 1ull;
  int cnt[8] = {0,0,0,0,0,0,0,0};
  #pragma unroll 2
  for (int s = 0; s < 64; ++s){
    int q = s * 64 + lane;
    float4 XY = posP[q * 2], ZW = posP[q * 2 + 1];
    f32x2 X = {XY.x, XY.y}, Y = {XY.z, XY.w}, Z = {ZW.x, ZW.y}, W = {ZW.z, ZW.w};
    int cand0 = q * 2;
    #pragma unroll
    for (int p = 0; p < 8; ++p){
      f32x2 v2 = pk_fma(nex2[p], X, W);
      v2 = pk_fma(ney2[p], Y, v2);
      v2 = pk_fma(nez2[p], Z, v2);
      bool h0 = v2.x <= tau0[p];
      bool h1 = v2.y <= tau0[p];
      if (__any(h0 || h1)){
        unsigned long long m0 = __ballot(h0);
        unsigned long long m1 = __ballot(h1);
        int base = cnt[p];
        int c0 = __popcll(m0);
        if (h0){
          int s0 = base + (int)__popcll(m0 & lmlt);
          if (s0 < 64){ lval[w][p][s0] = v2.x; lidx[w][p][s0] = cand0; }
        }
        if (h1){
          int s1 = base + c0 + (int)__popcll(m1 & lmlt);
          if (s1 < 64){ lval[w][p][s1] = v2.y; lidx[w][p][s1] = cand0 + 1; }
        }
        cnt[p] = base + c0 + (int)__popcll(m1);
      }
    }
  }
  if (lane == 0){
    #pragma unroll
    for (int p = 0; p < 8; ++p) cntL[w][p] = cnt[p];
  }
  __syncthreads();

  // finalize the wave's 8 points, pair-interleaved, 4 sequential rounds
  #pragma unroll 1
  for (int u = 0; u < 4; ++u){
    int p0 = u * 2, p1 = u * 2 + 1;
    int nA = n0 + p0, nB = n0 + p1;
    int c0 = cntL[w][p0]; if (c0 > 64) c0 = 64;
    int c1 = cntL[w][p1]; if (c1 > 64) c1 = 64;
    float va = (lane < c0) ? lval[w][p0][lane] : FMAXV;
    int   ia = (lane < c0) ? lidx[w][p0][lane] : 0x7fffffff;
    float vb = (lane < c1) ? lval[w][p1][lane] : FMAXV;
    int   ib = (lane < c1) ? lidx[w][p1][lane] : 0x7fffffff;

    // select-16 network: S1 sort 16-groups (alt dir by bit4), M1 min-merge xor16,
    // S2 resort bitonic-16 (dir by bit5), M2 min-merge xor32 -> exact top-16 in lanes 0..15
    #pragma unroll
    for (int k = 2; k <= 16; k <<= 1){
      #pragma unroll
      for (int j = k >> 1; j > 0; j >>= 1){
        bool keepmin = ((lane & k) == 0) == ((lane & j) == 0);
        { float pv = __shfl_xor(va, j); int pid = __shfl_xor(ia, j);
          bool pl = (pv < va) || (pv == va && pid < ia);
          if (keepmin ? pl : !pl){ va = pv; ia = pid; } }
        { float pv = __shfl_xor(vb, j); int pid = __shfl_xor(ib, j);
          bool pl = (pv < vb) || (pv == vb && pid < ib);
          if (keepmin ? pl : !pl){ vb = pv; ib = pid; } }
      }
    }
    { float pv = __shfl_xor(va, 16); int pid = __shfl_xor(ia, 16);
      if ((pv < va) || (pv == va && pid < ia)){ va = pv; ia = pid; } }
    { float pv = __shfl_xor(vb, 16); int pid = __shfl_xor(ib, 16);
      if ((pv < vb) || (pv == vb && pid < ib)){ vb = pv; ib = pid; } }
    #pragma unroll
    for (int j = 8; j > 0; j >>= 1){
      bool keepmin = ((lane & 32) == 0) == ((lane & j) == 0);
      { float pv = __shfl_xor(va, j); int pid = __shfl_xor(ia, j);
        bool pl = (pv < va) || (pv == va && pid < ia);
        if (keepmin ? pl : !pl){ va = pv; ia = pid; } }
      { float pv = __shfl_xor(vb, j); int pid = __shfl_xor(ib, j);
        bool pl = (pv < vb) || (pv == vb && pid < ib);
        if (keepmin ? pl : !pl){ vb = pv; ib = pid; } }
    }
    { float pv = __shfl_xor(va, 32); int pid = __shfl_xor(ia, 32);
      if ((pv < va) || (pv == va && pid < ia)){ va = pv; ia = pid; } }
    { float pv = __shfl_xor(vb, 32); int pid = __shfl_xor(ib, 32);
      if ((pv < vb) || (pv == vb && pid < ib)){ vb = pv; ib = pid; } }
    int topi0 = ia, topi1 = ib;

    // scores, both points: lane = part*16 + kk; 32-dim partial dot, ef read direct from
    // global (uniform within each 16-lane group -> single coalesced L2 fetch per segment)
    int kk = lane & 15, part = lane >> 4;
    int ik0 = __shfl(topi0, kk);
    int ik1 = __shfl(topi1, kk);
    const uint4*  zr0 = (const uint4*)((const u16*)Zd + (size_t)ik0 * 128) + part * 4;
    const uint4*  zr1 = (const uint4*)((const u16*)Zd + (size_t)ik1 * 128) + part * 4;
    const float4* e40 = (const float4*)(ef + (size_t)nA * 128) + part * 8;
    const float4* e41 = (const float4*)(ef + (size_t)nB * 128) + part * 8;
    float pr0 = 0.f, pr1 = 0.f;
    #pragma unroll
    for (int i = 0; i < 4; ++i){
      uint4 z0 = zr0[i], z1 = zr1[i];
      float4 ea0 = e40[2 * i], eb0 = e40[2 * i + 1];
      float4 ea1 = e41[2 * i], eb1 = e41[2 * i + 1];
      pr0 = fmaf(ea0.x, asfloat(z0.x << 16), pr0); pr0 = fmaf(ea0.y, asfloat(z0.x & 0xffff0000u), pr0);
      pr0 = fmaf(ea0.z, asfloat(z0.y << 16), pr0); pr0 = fmaf(ea0.w, asfloat(z0.y & 0xffff0000u), pr0);
      pr0 = fmaf(eb0.x, asfloat(z0.z << 16), pr0); pr0 = fmaf(eb0.y, asfloat(z0.z & 0xffff0000u), pr0);
      pr0 = fmaf(eb0.z, asfloat(z0.w << 16), pr0); pr0 = fmaf(eb0.w, asfloat(z0.w & 0xffff0000u), pr0);
      pr1 = fmaf(ea1.x, asfloat(z1.x << 16), pr1); pr1 = fmaf(ea1.y, asfloat(z1.x & 0xffff0000u), pr1);
      pr1 = fmaf(ea1.z, asfloat(z1.y << 16), pr1); pr1 = fmaf(ea1.w, asfloat(z1.y & 0xffff0000u), pr1);
      pr1 = fmaf(eb1.x, asfloat(z1.z << 16), pr1); pr1 = fmaf(eb1.y, asfloat(z1.z & 0xffff0000u), pr1);
      pr1 = fmaf(eb1.z, asfloat(z1.w << 16), pr1); pr1 = fmaf(eb1.w, asfloat(z1.w & 0xffff0000u), pr1);
    }
    pr0 += __shfl_xor(pr0, 16); pr1 += __shfl_xor(pr1, 16);
    pr0 += __shfl_xor(pr0, 32); pr1 += __shfl_xor(pr1, 32);
    float sc0 = (pr0 + bqK[ik0]) * (1.0f / 16.0f);   // replicated across the 4 parts
    float sc1 = (pr1 + bqK[ik1]) * (1.0f / 16.0f);

    float mx0 = sc0, mx1 = sc1;
    #pragma unroll
    for (int off = 8; off >= 1; off >>= 1){
      mx0 = fmaxf(mx0, __shfl_xor(mx0, off));
      mx1 = fmaxf(mx1, __shfl_xor(mx1, off));
    }
    float e0 = (lane < KNN) ? __expf(sc0 - mx0) : 0.f;
    float e1 = (lane < KNN) ? __expf(sc1 - mx1) : 0.f;
    float l0 = e0, l1 = e1;
    #pragma unroll
    for (int off = 8; off >= 1; off >>= 1){
      l0 += __shfl_xor(l0, off);
      l1 += __shfl_xor(l1, off);
    }
    float wgt0 = (lane < KNN) ? (e0 / l0) : 0.f;
    float wgt1 = (lane < KNN) ? (e1 / l1) : 0.f;

    float a00 = 0.f, a01 = 0.f, a10 = 0.f, a11 = 0.f;
    #pragma unroll
    for (int k = 0; k < KNN; ++k){
      int ikk0 = __shfl(topi0, k);
      int ikk1 = __shfl(topi1, k);
      float wk0 = __shfl(wgt0, k);
      float wk1 = __shfl(wgt1, k);
      ushort2 u0 = *(const ushort2*)((const u16*)Ud + (size_t)ikk0 * 128 + lane * 2);
      ushort2 u1 = *(const ushort2*)((const u16*)Ud + (size_t)ikk1 * 128 + lane * 2);
      a00 = fmaf(wk0, bfbits2f(u0.x), a00);
      a01 = fmaf(wk0, bfbits2f(u0.y), a01);
      a10 = fmaf(wk1, bfbits2f(u1.x), a10);
      a11 = fmaf(wk1, bfbits2f(u1.y), a11);
    }
    bf16 h00 = __float2bfloat16(a00), h01 = __float2bfloat16(a01);
    bf16 h10 = __float2bfloat16(a10), h11 = __float2bfloat16(a11);
    ushort2 st0; st0.x = *(u16*)&h00; st0.y = *(u16*)&h01;
    ushort2 st1; st1.x = *(u16*)&h10; st1.y = *(u16*)&h11;
    *(ushort2*)(hagg + (size_t)nA * 128 + lane * 2) = st0;
    *(ushort2*)(hagg + (size_t)nB * 128 + lane * 2) = st1;
  }
}

// ---------- fused MLP: h = relu(hagg + W1e@ef + b1) -> LDS; up = W2@h + b2; LN; out + tail ----------
__global__ __launch_bounds__(256) void k_mlp(const bf16* __restrict__ hagg,
                                             const float* __restrict__ ef,
                                             const float4* __restrict__ W1eSa,
                                             const float4* __restrict__ W1eSb,
                                             const float* __restrict__ b1,
                                             const float4* __restrict__ W2Sa,
                                             const float4* __restrict__ W2Sb,
                                             const float* __restrict__ b2,
                                             const float* __restrict__ lng, const float* __restrict__ lnb,
                                             const float* __restrict__ epos, const int* __restrict__ lab,
                                             float* __restrict__ out){
  __shared__ float hbuf[16 * 128];
  __shared__ float ubuf[16 * 128];
  __shared__ float stats[32];
  int t = threadIdx.x;
  int n0 = blockIdx.x * 16;
  {
    int gid = blockIdx.x * 256 + t;
    if (gid < NF){
      float* op = out + (size_t)NF * 128;
      op[gid * 3 + 0] = epos[gid * 3 + 0];
      op[gid * 3 + 1] = epos[gid * 3 + 1];
      op[gid * 3 + 2] = epos[gid * 3 + 2];
      out[(size_t)NF * 128 + (size_t)NF * 3 + gid] = (float)lab[gid];
    }
  }
  int jg = t & 63;
  int pg4 = __builtin_amdgcn_readfirstlane((t >> 6) * 4);
  int j0 = jg * 2;
  float acc[2][4];
  #pragma unroll
  for (int a = 0; a < 2; ++a)
    #pragma unroll
    for (int p = 0; p < 4; ++p) acc[a][p] = 0.f;
  for (int c4 = 0; c4 < 32; ++c4){
    float4 wa = W1eSa[c4 * 64 + jg];
    float4 wb = W1eSb[c4 * 64 + jg];
    #pragma unroll
    for (int p = 0; p < 4; ++p){
      float4 x = ((const float4*)(ef + (size_t)(n0 + pg4 + p) * 128))[c4];
      acc[0][p] += wa.x*x.x + wa.y*x.y + wa.z*x.z + wa.w*x.w;
      acc[1][p] += wb.x*x.x + wb.y*x.y + wb.z*x.z + wb.w*x.w;
    }
  }
  float b1a = b1[j0], b1b = b1[j0 + 1];
  #pragma unroll
  for (int p = 0; p < 4; ++p){
    size_t row = (size_t)(n0 + pg4 + p);
    ushort2 hgv = *(const ushort2*)((const u16*)hagg + row * 128 + j0);
    hbuf[(pg4 + p) * 128 + j0]     = fmaxf(acc[0][p] + b1a + bfbits2f(hgv.x), 0.f);
    hbuf[(pg4 + p) * 128 + j0 + 1] = fmaxf(acc[1][p] + b1b + bfbits2f(hgv.y), 0.f);
  }
  __syncthreads();
  float acc2[2][4];
  #pragma unroll
  for (int a = 0; a < 2; ++a)
    #pragma unroll
    for (int p = 0; p < 4; ++p) acc2[a][p] = 0.f;
  const float4* hb4 = (const float4*)hbuf;
  for (int c4 = 0; c4 < 32; ++c4){
    float4 wa = W2Sa[c4 * 64 + jg];
    float4 wb = W2Sb[c4 * 64 + jg];
    #pragma unroll
    for (int p = 0; p < 4; ++p){
      float4 x = hb4[(pg4 + p) * 32 + c4];
      acc2[0][p] += wa.x*x.x + wa.y*x.y + wa.z*x.z + wa.w*x.w;
      acc2[1][p] += wb.x*x.x + wb.y*x.y + wb.z*x.z + wb.w*x.w;
    }
  }
  float b2a = b2[j0], b2b = b2[j0 + 1];
  float u[2][4];
  #pragma unroll
  for (int p = 0; p < 4; ++p){
    u[0][p] = acc2[0][p] + b2a;
    u[1][p] = acc2[1][p] + b2b;
    ubuf[(pg4 + p) * 128 + j0]     = u[0][p];
    ubuf[(pg4 + p) * 128 + j0 + 1] = u[1][p];
  }
  __syncthreads();
  {
    int p = t >> 4, qi = t & 15;
    const float* ub = &ubuf[p * 128 + qi * 8];
    float s = 0.f, s2 = 0.f;
    #pragma unroll
    for (int e2i = 0; e2i < 8; ++e2i){ float v = ub[e2i]; s += v; s2 += v * v; }
    #pragma unroll
    for (int off = 1; off < 16; off <<= 1){ s += __shfl_xor(s, off); s2 += __shfl_xor(s2, off); }
    if (qi == 0){
      float mu = s * (1.f / 128.f);
      float var = s2 * (1.f / 128.f) - mu * mu;
      stats[p] = mu;
      stats[16 + p] = rsqrtf(fmaxf(var, 0.f) + 1e-5f);
    }
  }
  __syncthreads();
  float ga = lng[j0], gb = lng[j0 + 1];
  float ba = lnb[j0], bbv = lnb[j0 + 1];
  #pragma unroll
  for (int p = 0; p < 4; ++p){
    float mu = stats[pg4 + p], rs = stats[16 + pg4 + p];
    out[(size_t)(n0 + pg4 + p) * 128 + j0]     = (u[0][p] - mu) * rs * ga + ba;
    out[(size_t)(n0 + pg4 + p) * 128 + j0 + 1] = (u[1][p] - mu) * rs * gb + bbv;
  }
}

extern "C" void kernel_launch(void* const* d_in, const int* in_sizes, int n_in,
                              void* d_out, int out_size, void* d_ws, size_t ws_size,
                              hipStream_t stream){
  const float* df   = (const float*)d_in[0];
  const float* dpos = (const float*)d_in[1];
  const float* ef   = (const float*)d_in[2];
  const float* epos = (const float*)d_in[3];
  const int*   lab  = (const int*)d_in[4];
  const float* Wq = (const float*)d_in[5];
  const float* bq = (const float*)d_in[6];
  const float* Wk = (const float*)d_in[7];
  const float* bk = (const float*)d_in[8];
  const float* Wv = (const float*)d_in[9];
  const float* bv = (const float*)d_in[10];
  const float* W1 = (const float*)d_in[11];
  const float* b1 = (const float*)d_in[12];
  const float* W2 = (const float*)d_in[13];
  const float* b2 = (const float*)d_in[14];
  const float* lng = (const float*)d_in[15];
  const float* lnb = (const float*)d_in[16];
  float* out = (float*)d_out;

  // workspace layout (~12.6 MB)
  char* wsb = (char*)d_ws;
  float4* posP  = (float4*)(wsb);                    // 128 KB
  bf16*   Zd    = (bf16*)(wsb + 131072);             // 2 MB
  bf16*   Ud    = (bf16*)(wsb + 2228224);            // 2 MB
  float*  bqK   = (float*)(wsb + 4325376);           // 32 KB
  bf16*   hagg  = (bf16*)(wsb + 4358144);            // 8 MB
  float4* W1eSa = (float4*)(wsb + 12746752);         // 32 KB
  float4* W1eSb = (float4*)(wsb + 12779520);         // 32 KB
  float4* W2Sa  = (float4*)(wsb + 12812288);         // 32 KB
  float4* W2Sb  = (float4*)(wsb + 12845056);         // 32 KB
  float*  WkqS  = (float*)(wsb + 12877824);          // 128 KB
  float*  WvuS  = (float*)(wsb + 13008896);          // 128 KB
  float*  bkq   = (float*)(wsb + 13139968);          // 512 B
  float*  bvu   = (float*)(wsb + 13140480);          // 512 B
  float*  wbq   = (float*)(wsb + 13140992);          // 1 KB
  float*  sbq   = (float*)(wsb + 13142016);          // 4 B

  k_prep  <<<64,   256, 0, stream>>>(dpos, W1, W2, posP, W1eSa, W1eSb, W2Sa, W2Sb);
  k_wprod <<<1028, 256, 0, stream>>>(Wk, Wv, Wq, W1, bk, bv, bq, WkqS, WvuS, bkq, bvu, wbq, sbq);
  k_dec   <<<NC / 8, 256, 0, stream>>>(df, (const float4*)WkqS, (const float4*)WvuS, bkq, bvu, wbq, sbq, Zd, Ud, bqK);
  k_attn  <<<NF / 16, 128, 0, stream>>>(epos, posP, ef, Zd, Ud, bqK, hagg);
  k_mlp   <<<NF / 16, 256, 0, stream>>>(hagg, ef, W1eSa, W1eSb, b1, W2Sa, W2Sb, b2, lng, lnb, epos, lab, out);
  (void)in_sizes; (void)n_in; (void)out_size; (void)ws_size;
}

// Round 4
// 339.689 us; speedup vs baseline: 1.0625x; 1.0625x over previous
//
#include <hip/hip_runtime.h>
#include <hip/hip_bf16.h>

typedef __hip_bfloat16 bf16;
typedef unsigned short u16;
typedef float f32x2 __attribute__((ext_vector_type(2)));

#define NC 8192
#define NF 32768
#define KNN 16
#define FMAXV 3.402823466e+38f

__device__ __forceinline__ float bfbits2f(u16 u){
  union { unsigned u; float f; } x; x.u = ((unsigned)u) << 16; return x.f;
}
__device__ __forceinline__ float asfloat(unsigned u){
  union { unsigned u; float f; } x; x.u = u; return x.f;
}
// packed fp32 fma: d = a*b + c on both halves (IEEE fma per half, bit-exact vs fmaf)
__device__ __forceinline__ f32x2 pk_fma(f32x2 a, f32x2 b, f32x2 c){
  f32x2 d;
  asm("v_pk_fma_f32 %0, %1, %2, %3" : "=v"(d) : "v"(a), "v"(b), "v"(c));
  return d;
}

// ---------- k_prep: paired-candidate pos layout + MLP weight swizzles (grid 64 x 256 = 16384) ----------
// posP[2q]   = (x_{2q}, x_{2q+1}, y_{2q}, y_{2q+1})
// posP[2q+1] = (z_{2q}, z_{2q+1}, w_{2q}, w_{2q+1})   w = |d|^2/2
__global__ __launch_bounds__(256) void k_prep(const float* __restrict__ dpos,
                                              const float* __restrict__ W1,
                                              const float* __restrict__ W2,
                                              float4* __restrict__ posP,
                                              float4* __restrict__ W1eSa,
                                              float4* __restrict__ W1eSb,
                                              float4* __restrict__ W2Sa,
                                              float4* __restrict__ W2Sb){
  int g = blockIdx.x * 256 + threadIdx.x;
  if (g < 4096){
    const float2* dp2 = (const float2*)(dpos + (size_t)g * 6);
    float2 a = dp2[0], b = dp2[1], c = dp2[2];
    float x0 = a.x, y0 = a.y, z0 = b.x;
    float x1 = b.y, y1 = c.x, z1 = c.y;
    float dd0 = __fadd_rn(__fadd_rn(__fmul_rn(x0,x0), __fmul_rn(y0,y0)), __fmul_rn(z0,z0));
    float dd1 = __fadd_rn(__fadd_rn(__fmul_rn(x1,x1), __fmul_rn(y1,y1)), __fmul_rn(z1,z1));
    posP[g * 2]     = make_float4(x0, x1, y0, y1);
    posP[g * 2 + 1] = make_float4(z0, z1, dd0 * 0.5f, dd1 * 0.5f);
  } else if (g >= 8192 && g < 10240){
    int f = g - 8192; int c4 = f >> 6, jg = f & 63;
    W1eSa[f] = ((const float4*)(W1 + (size_t)(2 * jg) * 384 + 256))[c4];
  } else if (g >= 10240 && g < 12288){
    int f = g - 10240; int c4 = f >> 6, jg = f & 63;
    W1eSb[f] = ((const float4*)(W1 + (size_t)(2 * jg + 1) * 384 + 256))[c4];
  } else if (g >= 12288 && g < 14336){
    int f = g - 12288; int c4 = f >> 6, jg = f & 63;
    W2Sa[f] = ((const float4*)(W2 + (size_t)(2 * jg) * 128))[c4];
  } else if (g >= 14336){
    int f = g - 14336; int c4 = f >> 6, jg = f & 63;
    W2Sb[f] = ((const float4*)(W2 + (size_t)(2 * jg + 1) * 128))[c4];
  }
}

// ---------- k_wprod: weight-product fold, 4-way K-split for TLP (grid 257*4 = 1028) ----------
__global__ __launch_bounds__(256) void k_wprod(const float* __restrict__ Wk,
                                               const float* __restrict__ Wv,
                                               const float* __restrict__ Wq,
                                               const float* __restrict__ W1,
                                               const float* __restrict__ bk,
                                               const float* __restrict__ bv,
                                               const float* __restrict__ bq,
                                               float* __restrict__ WkqS,
                                               float* __restrict__ WvuS,
                                               float* __restrict__ bkq,
                                               float* __restrict__ bvu,
                                               float* __restrict__ wbq,
                                               float* __restrict__ sbq){
  __shared__ float partial[256];
  __shared__ float red[256];
  int B = blockIdx.x, t = threadIdx.x;
  int csel = B >> 2, tch = B & 3;
  int o = (t & 63) + tch * 64;
  int q = t >> 6;
  int j0 = q * 64;
  if (csel < 128){
    int c = csel;
    float acc = 0.f;
    for (int j = j0; j < j0 + 64; ++j)
      acc = fmaf(Wk[(size_t)j * 256 + o], Wq[(size_t)j * 128 + c], acc);
    partial[t] = acc;
    if (tch == 0) red[t] = bk[t] * Wq[(size_t)t * 128 + c];
    __syncthreads();
    if (t < 64){
      float a = partial[t] + partial[t + 64] + partial[t + 128] + partial[t + 192];
      WkqS[(size_t)((o >> 2) * 128 + c) * 4 + (o & 3)] = a;
    }
    if (tch == 0){
      for (int s = 128; s > 0; s >>= 1){ if (t < s) red[t] += red[t + s]; __syncthreads(); }
      if (t == 0) bkq[c] = red[0];
    }
  } else if (csel < 256){
    int h = csel - 128;
    float acc = 0.f;
    for (int j = j0; j < j0 + 64; ++j)
      acc = fmaf(Wv[(size_t)j * 256 + o], W1[(size_t)h * 384 + j], acc);
    partial[t] = acc;
    if (tch == 0) red[t] = bv[t] * W1[(size_t)h * 384 + t];
    __syncthreads();
    if (t < 64){
      float a = partial[t] + partial[t + 64] + partial[t + 128] + partial[t + 192];
      WvuS[(size_t)((o >> 2) * 128 + h) * 4 + (o & 3)] = a;
    }
    if (tch == 0){
      for (int s = 128; s > 0; s >>= 1){ if (t < s) red[t] += red[t + s]; __syncthreads(); }
      if (t == 0) bvu[h] = red[0];
    }
  } else {
    float acc = 0.f;
    for (int j = j0; j < j0 + 64; ++j)
      acc = fmaf(Wk[(size_t)j * 256 + o], bq[j], acc);
    partial[t] = acc;
    if (tch == 0) red[t] = bk[t] * bq[t];
    __syncthreads();
    if (t < 64){
      float a = partial[t] + partial[t + 64] + partial[t + 128] + partial[t + 192];
      wbq[o] = a;
    }
    if (tch == 0){
      for (int s = 128; s > 0; s >>= 1){ if (t < s) red[t] += red[t + s]; __syncthreads(); }
      if (t == 0) sbq[0] = red[0];
    }
  }
}

// ---------- k_dec: Zd = df@Wkq + bkq, Ud = df@Wvu + bvu, bqK = df@wbq + sbq (8 rows/block) ----------
__global__ __launch_bounds__(256) void k_dec(const float* __restrict__ df,
                                             const float4* __restrict__ WkqS,
                                             const float4* __restrict__ WvuS,
                                             const float* __restrict__ bkq,
                                             const float* __restrict__ bvu,
                                             const float* __restrict__ wbq,
                                             const float* __restrict__ sbq,
                                             bf16* __restrict__ Zd, bf16* __restrict__ Ud,
                                             float* __restrict__ bqK){
  __shared__ float part[8][32];
  int t = threadIdx.x;
  int g0 = blockIdx.x * 8;
  int half = __builtin_amdgcn_readfirstlane(t >> 7);
  int c = t & 127;
  const float4* W = half ? WvuS : WkqS;
  float acc[8];
  #pragma unroll
  for (int p = 0; p < 8; ++p) acc[p] = 0.f;
  for (int j4 = 0; j4 < 64; ++j4){
    float4 w = W[j4 * 128 + c];
    #pragma unroll
    for (int p = 0; p < 8; ++p){
      float4 a = ((const float4*)(df + (size_t)(g0 + p) * 256))[j4];
      acc[p] += w.x*a.x + w.y*a.y + w.z*a.z + w.w*a.w;
    }
  }
  float bias = half ? bvu[c] : bkq[c];
  bf16* dst = half ? Ud : Zd;
  #pragma unroll
  for (int p = 0; p < 8; ++p)
    dst[(size_t)(g0 + p) * 128 + c] = __float2bfloat16(acc[p] + bias);
  {
    int r = t >> 5, seg = t & 31;
    float s = 0.f;
    const float* dr = df + (size_t)(g0 + r) * 256 + seg * 8;
    const float* wq = wbq + seg * 8;
    #pragma unroll
    for (int e = 0; e < 8; ++e) s = fmaf(dr[e], wq[e], s);
    part[r][seg] = s;
  }
  __syncthreads();
  if (t < 8){
    float s = sbq[0];
    #pragma unroll
    for (int seg = 0; seg < 32; ++seg) s += part[t][seg];
    bqK[g0 + t] = s;
  }
}

// ---------- k_knn: exact top-16 indices per fine point (round-2 structure, attention removed) ----------
// 8 points/block, candidates split across 4 waves. tau0 = 17th smallest of the pooled union of
// per-wave sorted 16-runs (11-stage merge). Pass B appends via LDS atomics; select-16 network
// yields the exact (val,idx) top-16 set in lanes 0..15; indices written to knnI.
__global__ __launch_bounds__(256) void k_knn(const float* __restrict__ epos,
                                             const float4* __restrict__ posP,
                                             int* __restrict__ knnI){
  __shared__ float smin[8 * 64];
  __shared__ float tauLDS[8];
  __shared__ int   cnt[8];
  __shared__ float lval[8][64];
  __shared__ int   lidx[8][64];

  int t = threadIdx.x, lane = t & 63, w = t >> 6;
  int n0 = blockIdx.x * 8;
  f32x2 nex2[8], ney2[8], nez2[8];
  #pragma unroll
  for (int p = 0; p < 8; ++p){
    float nx = -epos[(n0 + p) * 3 + 0];
    float ny = -epos[(n0 + p) * 3 + 1];
    float nz = -epos[(n0 + p) * 3 + 2];
    nex2[p].x = nx; nex2[p].y = nx;
    ney2[p].x = ny; ney2[p].y = ny;
    nez2[p].x = nz; nez2[p].y = nz;
  }
  const float4* base = posP + w * 2048;   // wave's 1024 candidate-pairs = 2048 float4

  // PASS A: per-lane minima over 2 packed candidates/iter (3 pk_fma + 2 min per point)
  f32x2 vmin2[8];
  #pragma unroll
  for (int p = 0; p < 8; ++p){ vmin2[p].x = FMAXV; vmin2[p].y = FMAXV; }
  #pragma unroll 2
  for (int s = 0; s < 16; ++s){
    int q2 = (s * 64 + lane) * 2;
    float4 XY = base[q2], ZW = base[q2 + 1];
    f32x2 X = {XY.x, XY.y}, Y = {XY.z, XY.w}, Z = {ZW.x, ZW.y}, W = {ZW.z, ZW.w};
    #pragma unroll
    for (int p = 0; p < 8; ++p){
      f32x2 v2 = pk_fma(nex2[p], X, W);
      v2 = pk_fma(ney2[p], Y, v2);
      v2 = pk_fma(nez2[p], Z, v2);
      vmin2[p].x = fminf(vmin2[p].x, v2.x);
      vmin2[p].y = fminf(vmin2[p].y, v2.y);
    }
  }
  float vmin[8];
  #pragma unroll
  for (int p = 0; p < 8; ++p) vmin[p] = fminf(vmin2[p].x, vmin2[p].y);

  // full bitonic sort of 64 lane-minima, 8 point-registers at once (lanes 0..15 -> ascending top-16)
  #pragma unroll
  for (int k = 2; k <= 64; k <<= 1){
    #pragma unroll
    for (int j = k >> 1; j > 0; j >>= 1){
      bool keepmin = ((lane & j) == 0) == ((lane & k) == 0);
      #pragma unroll
      for (int p = 0; p < 8; ++p){
        float pv = __shfl_xor(vmin[p], j);
        vmin[p] = keepmin ? fminf(vmin[p], pv) : fmaxf(vmin[p], pv);
      }
    }
  }
  if (lane < 16){
    #pragma unroll
    for (int p = 0; p < 8; ++p) smin[p * 64 + w * 16 + lane] = vmin[p];
  }
  if (t < 8) cnt[t] = 0;
  __syncthreads();

  // union 17th-smallest for points 2w, 2w+1 (interleaved).
  // smin holds 4 ascending 16-runs per point; read odd groups reversed -> two bitonic-32s,
  // merge-32 (dir by bit5) then merge-64 ascending: 11 stages total. tau = lane 16.
  {
    int src = (lane & 16) ? (lane ^ 15) : lane;
    float v0 = smin[(w * 2 + 0) * 64 + src];
    float v1 = smin[(w * 2 + 1) * 64 + src];
    #pragma unroll
    for (int j = 16; j > 0; j >>= 1){
      bool keepmin = ((lane & 32) == 0) == ((lane & j) == 0);
      float p0 = __shfl_xor(v0, j); v0 = keepmin ? fminf(v0, p0) : fmaxf(v0, p0);
      float p1 = __shfl_xor(v1, j); v1 = keepmin ? fminf(v1, p1) : fmaxf(v1, p1);
    }
    #pragma unroll
    for (int j = 32; j > 0; j >>= 1){
      bool keepmin = ((lane & j) == 0);
      float p0 = __shfl_xor(v0, j); v0 = keepmin ? fminf(v0, p0) : fmaxf(v0, p0);
      float p1 = __shfl_xor(v1, j); v1 = keepmin ? fminf(v1, p1) : fmaxf(v1, p1);
    }
    if (lane == 16){ tauLDS[w * 2] = v0; tauLDS[w * 2 + 1] = v1; }
  }
  __syncthreads();
  float tau0[8];
  #pragma unroll
  for (int p = 0; p < 8; ++p) tau0[p] = tauLDS[p];

  // PASS B: filtered append (identical packed val expression)
  #pragma unroll 2
  for (int s = 0; s < 16; ++s){
    int q = s * 64 + lane;
    float4 XY = base[q * 2], ZW = base[q * 2 + 1];
    f32x2 X = {XY.x, XY.y}, Y = {XY.z, XY.w}, Z = {ZW.x, ZW.y}, W = {ZW.z, ZW.w};
    int cand0 = w * 2048 + q * 2;
    #pragma unroll
    for (int p = 0; p < 8; ++p){
      f32x2 v2 = pk_fma(nex2[p], X, W);
      v2 = pk_fma(ney2[p], Y, v2);
      v2 = pk_fma(nez2[p], Z, v2);
      if (v2.x <= tau0[p]){
        int slot = atomicAdd(&cnt[p], 1);
        if (slot < 64){ lval[p][slot] = v2.x; lidx[p][slot] = cand0; }
      }
      if (v2.y <= tau0[p]){
        int slot = atomicAdd(&cnt[p], 1);
        if (slot < 64){ lval[p][slot] = v2.y; lidx[p][slot] = cand0 + 1; }
      }
    }
  }
  __syncthreads();

  // finalize points 2w, 2w+1 interleaved: exact (val,idx) select-16, write indices
  {
    int p0 = w * 2, p1 = w * 2 + 1;
    int nA = n0 + p0, nB = n0 + p1;
    int c0 = cnt[p0]; if (c0 > 64) c0 = 64;
    int c1 = cnt[p1]; if (c1 > 64) c1 = 64;
    float va = (lane < c0) ? lval[p0][lane] : FMAXV;
    int   ia = (lane < c0) ? lidx[p0][lane] : 0x7fffffff;
    float vb = (lane < c1) ? lval[p1][lane] : FMAXV;
    int   ib = (lane < c1) ? lidx[p1][lane] : 0x7fffffff;

    // select-16 network: S1 sort 16-groups (alt dir by bit4), M1 min-merge xor16,
    // S2 resort bitonic-16 (dir by bit5), M2 min-merge xor32 -> exact top-16 in lanes 0..15
    #pragma unroll
    for (int k = 2; k <= 16; k <<= 1){
      #pragma unroll
      for (int j = k >> 1; j > 0; j >>= 1){
        bool keepmin = ((lane & k) == 0) == ((lane & j) == 0);
        { float pv = __shfl_xor(va, j); int pid = __shfl_xor(ia, j);
          bool pl = (pv < va) || (pv == va && pid < ia);
          if (keepmin ? pl : !pl){ va = pv; ia = pid; } }
        { float pv = __shfl_xor(vb, j); int pid = __shfl_xor(ib, j);
          bool pl = (pv < vb) || (pv == vb && pid < ib);
          if (keepmin ? pl : !pl){ vb = pv; ib = pid; } }
      }
    }
    { float pv = __shfl_xor(va, 16); int pid = __shfl_xor(ia, 16);
      if ((pv < va) || (pv == va && pid < ia)){ va = pv; ia = pid; } }
    { float pv = __shfl_xor(vb, 16); int pid = __shfl_xor(ib, 16);
      if ((pv < vb) || (pv == vb && pid < ib)){ vb = pv; ib = pid; } }
    #pragma unroll
    for (int j = 8; j > 0; j >>= 1){
      bool keepmin = ((lane & 32) == 0) == ((lane & j) == 0);
      { float pv = __shfl_xor(va, j); int pid = __shfl_xor(ia, j);
        bool pl = (pv < va) || (pv == va && pid < ia);
        if (keepmin ? pl : !pl){ va = pv; ia = pid; } }
      { float pv = __shfl_xor(vb, j); int pid = __shfl_xor(ib, j);
        bool pl = (pv < vb) || (pv == vb && pid < ib);
        if (keepmin ? pl : !pl){ vb = pv; ib = pid; } }
    }
    { float pv = __shfl_xor(va, 32); int pid = __shfl_xor(ia, 32);
      if ((pv < va) || (pv == va && pid < ia)){ va = pv; ia = pid; } }
    { float pv = __shfl_xor(vb, 32); int pid = __shfl_xor(ib, 32);
      if ((pv < vb) || (pv == vb && pid < ib)){ vb = pv; ib = pid; } }

    if (lane < 16){
      knnI[(size_t)nA * 16 + lane] = ia;
      knnI[(size_t)nB * 16 + lane] = ib;
    }
  }
}

// ---------- k_amlp: fused attention read-out + MLP + LN + tail ----------
// Phase 1 (attention): 16 lanes per point; lane kk owns neighbor kk. Full 128-dot per lane
// (no cross-lane reduce), softmax via 4-step shfl within the 16-group, agg gathers Ud rows
// fully coalesced (16 lanes x 16B = one 256B row), result -> haggL in LDS (fp32).
// Phase 2: h = relu(haggL + W1e@ef + b1); up = W2@h + b2; LN; out.
__global__ __launch_bounds__(256) void k_amlp(const int* __restrict__ knnI,
                                              const bf16* __restrict__ Zd,
                                              const bf16* __restrict__ Ud,
                                              const float* __restrict__ bqK,
                                              const float* __restrict__ ef,
                                              const float4* __restrict__ W1eSa,
                                              const float4* __restrict__ W1eSb,
                                              const float* __restrict__ b1,
                                              const float4* __restrict__ W2Sa,
                                              const float4* __restrict__ W2Sb,
                                              const float* __restrict__ b2,
                                              const float* __restrict__ lng, const float* __restrict__ lnb,
                                              const float* __restrict__ epos, const int* __restrict__ lab,
                                              float* __restrict__ out){
  __shared__ float haggL[16 * 128];
  __shared__ float hbuf[16 * 128];
  __shared__ float ubuf[16 * 128];
  __shared__ float stats[32];
  int t = threadIdx.x;
  int n0 = blockIdx.x * 16;
  int lane = t & 63, w = t >> 6;
  {
    int gid = blockIdx.x * 256 + t;
    if (gid < NF){
      float* op = out + (size_t)NF * 128;
      op[gid * 3 + 0] = epos[gid * 3 + 0];
      op[gid * 3 + 1] = epos[gid * 3 + 1];
      op[gid * 3 + 2] = epos[gid * 3 + 2];
      out[(size_t)NF * 128 + (size_t)NF * 3 + gid] = (float)lab[gid];
    }
  }

  // ---- attention phase: point pp = w*4 + (lane>>4), neighbor slot kk = lane&15 ----
  {
    int kk = lane & 15;
    int pp = w * 4 + (lane >> 4);
    int n = n0 + pp;
    int ik = knnI[(size_t)n * 16 + kk];
    const uint4*  zr = (const uint4*)((const u16*)Zd + (size_t)ik * 128);
    const float4* e4 = (const float4*)(ef + (size_t)n * 128);
    float pr = 0.f;
    #pragma unroll
    for (int i = 0; i < 16; ++i){
      uint4 z = zr[i];
      float4 ea = e4[2 * i], eb = e4[2 * i + 1];
      pr = fmaf(ea.x, asfloat(z.x << 16), pr); pr = fmaf(ea.y, asfloat(z.x & 0xffff0000u), pr);
      pr = fmaf(ea.z, asfloat(z.y << 16), pr); pr = fmaf(ea.w, asfloat(z.y & 0xffff0000u), pr);
      pr = fmaf(eb.x, asfloat(z.z << 16), pr); pr = fmaf(eb.y, asfloat(z.z & 0xffff0000u), pr);
      pr = fmaf(eb.z, asfloat(z.w << 16), pr); pr = fmaf(eb.w, asfloat(z.w & 0xffff0000u), pr);
    }
    float sc = (pr + bqK[ik]) * (1.0f / 16.0f);
    float mx = sc;
    #pragma unroll
    for (int off = 1; off < 16; off <<= 1) mx = fmaxf(mx, __shfl_xor(mx, off));
    float e = __expf(sc - mx);
    float l = e;
    #pragma unroll
    for (int off = 1; off < 16; off <<= 1) l += __shfl_xor(l, off);
    float wgt = e / l;

    float acc8[8];
    #pragma unroll
    for (int j = 0; j < 8; ++j) acc8[j] = 0.f;
    int gbase = lane & 48;
    #pragma unroll
    for (int k2 = 0; k2 < 16; ++k2){
      int src = gbase | k2;
      float wk = __shfl(wgt, src);
      int ikk = __shfl(ik, src);
      uint4 uu = *(const uint4*)((const u16*)Ud + (size_t)ikk * 128 + kk * 8);
      acc8[0] = fmaf(wk, asfloat(uu.x << 16), acc8[0]);
      acc8[1] = fmaf(wk, asfloat(uu.x & 0xffff0000u), acc8[1]);
      acc8[2] = fmaf(wk, asfloat(uu.y << 16), acc8[2]);
      acc8[3] = fmaf(wk, asfloat(uu.y & 0xffff0000u), acc8[3]);
      acc8[4] = fmaf(wk, asfloat(uu.z << 16), acc8[4]);
      acc8[5] = fmaf(wk, asfloat(uu.z & 0xffff0000u), acc8[5]);
      acc8[6] = fmaf(wk, asfloat(uu.w << 16), acc8[6]);
      acc8[7] = fmaf(wk, asfloat(uu.w & 0xffff0000u), acc8[7]);
    }
    float4* hp = (float4*)&haggL[pp * 128 + kk * 8];
    hp[0] = make_float4(acc8[0], acc8[1], acc8[2], acc8[3]);
    hp[1] = make_float4(acc8[4], acc8[5], acc8[6], acc8[7]);
  }

  // ---- MLP phase ----
  int jg = t & 63;
  int pg4 = __builtin_amdgcn_readfirstlane((t >> 6) * 4);
  int j0 = jg * 2;
  float acc[2][4];
  #pragma unroll
  for (int a = 0; a < 2; ++a)
    #pragma unroll
    for (int p = 0; p < 4; ++p) acc[a][p] = 0.f;
  for (int c4 = 0; c4 < 32; ++c4){
    float4 wa = W1eSa[c4 * 64 + jg];
    float4 wb = W1eSb[c4 * 64 + jg];
    #pragma unroll
    for (int p = 0; p < 4; ++p){
      float4 x = ((const float4*)(ef + (size_t)(n0 + pg4 + p) * 128))[c4];
      acc[0][p] += wa.x*x.x + wa.y*x.y + wa.z*x.z + wa.w*x.w;
      acc[1][p] += wb.x*x.x + wb.y*x.y + wb.z*x.z + wb.w*x.w;
    }
  }
  __syncthreads();   // haggL ready
  float b1a = b1[j0], b1b = b1[j0 + 1];
  #pragma unroll
  for (int p = 0; p < 4; ++p){
    float2 hgv = *(const float2*)&haggL[(pg4 + p) * 128 + j0];
    hbuf[(pg4 + p) * 128 + j0]     = fmaxf(acc[0][p] + b1a + hgv.x, 0.f);
    hbuf[(pg4 + p) * 128 + j0 + 1] = fmaxf(acc[1][p] + b1b + hgv.y, 0.f);
  }
  __syncthreads();
  float acc2[2][4];
  #pragma unroll
  for (int a = 0; a < 2; ++a)
    #pragma unroll
    for (int p = 0; p < 4; ++p) acc2[a][p] = 0.f;
  const float4* hb4 = (const float4*)hbuf;
  for (int c4 = 0; c4 < 32; ++c4){
    float4 wa = W2Sa[c4 * 64 + jg];
    float4 wb = W2Sb[c4 * 64 + jg];
    #pragma unroll
    for (int p = 0; p < 4; ++p){
      float4 x = hb4[(pg4 + p) * 32 + c4];
      acc2[0][p] += wa.x*x.x + wa.y*x.y + wa.z*x.z + wa.w*x.w;
      acc2[1][p] += wb.x*x.x + wb.y*x.y + wb.z*x.z + wb.w*x.w;
    }
  }
  float b2a = b2[j0], b2b = b2[j0 + 1];
  float u[2][4];
  #pragma unroll
  for (int p = 0; p < 4; ++p){
    u[0][p] = acc2[0][p] + b2a;
    u[1][p] = acc2[1][p] + b2b;
    ubuf[(pg4 + p) * 128 + j0]     = u[0][p];
    ubuf[(pg4 + p) * 128 + j0 + 1] = u[1][p];
  }
  __syncthreads();
  {
    int p = t >> 4, qi = t & 15;
    const float* ub = &ubuf[p * 128 + qi * 8];
    float s = 0.f, s2 = 0.f;
    #pragma unroll
    for (int e2i = 0; e2i < 8; ++e2i){ float v = ub[e2i]; s += v; s2 += v * v; }
    #pragma unroll
    for (int off = 1; off < 16; off <<= 1){ s += __shfl_xor(s, off); s2 += __shfl_xor(s2, off); }
    if (qi == 0){
      float mu = s * (1.f / 128.f);
      float var = s2 * (1.f / 128.f) - mu * mu;
      stats[p] = mu;
      stats[16 + p] = rsqrtf(fmaxf(var, 0.f) + 1e-5f);
    }
  }
  __syncthreads();
  float ga = lng[j0], gb = lng[j0 + 1];
  float ba = lnb[j0], bbv = lnb[j0 + 1];
  #pragma unroll
  for (int p = 0; p < 4; ++p){
    float mu = stats[pg4 + p], rs = stats[16 + pg4 + p];
    out[(size_t)(n0 + pg4 + p) * 128 + j0]     = (u[0][p] - mu) * rs * ga + ba;
    out[(size_t)(n0 + pg4 + p) * 128 + j0 + 1] = (u[1][p] - mu) * rs * gb + bbv;
  }
}

extern "C" void kernel_launch(void* const* d_in, const int* in_sizes, int n_in,
                              void* d_out, int out_size, void* d_ws, size_t ws_size,
                              hipStream_t stream){
  const float* df   = (const float*)d_in[0];
  const float* dpos = (const float*)d_in[1];
  const float* ef   = (const float*)d_in[2];
  const float* epos = (const float*)d_in[3];
  const int*   lab  = (const int*)d_in[4];
  const float* Wq = (const float*)d_in[5];
  const float* bq = (const float*)d_in[6];
  const float* Wk = (const float*)d_in[7];
  const float* bk = (const float*)d_in[8];
  const float* Wv = (const float*)d_in[9];
  const float* bv = (const float*)d_in[10];
  const float* W1 = (const float*)d_in[11];
  const float* b1 = (const float*)d_in[12];
  const float* W2 = (const float*)d_in[13];
  const float* b2 = (const float*)d_in[14];
  const float* lng = (const float*)d_in[15];
  const float* lnb = (const float*)d_in[16];
  float* out = (float*)d_out;

  // workspace layout (~13.2 MB)
  char* wsb = (char*)d_ws;
  float4* posP  = (float4*)(wsb);                    // 128 KB
  bf16*   Zd    = (bf16*)(wsb + 131072);             // 2 MB
  bf16*   Ud    = (bf16*)(wsb + 2228224);            // 2 MB
  float*  bqK   = (float*)(wsb + 4325376);           // 32 KB
  int*    knnI  = (int*)(wsb + 4358144);             // 2 MB (NF*16*4)
  float4* W1eSa = (float4*)(wsb + 12746752);         // 32 KB
  float4* W1eSb = (float4*)(wsb + 12779520);         // 32 KB
  float4* W2Sa  = (float4*)(wsb + 12812288);         // 32 KB
  float4* W2Sb  = (float4*)(wsb + 12845056);         // 32 KB
  float*  WkqS  = (float*)(wsb + 12877824);          // 128 KB
  float*  WvuS  = (float*)(wsb + 13008896);          // 128 KB
  float*  bkq   = (float*)(wsb + 13139968);          // 512 B
  float*  bvu   = (float*)(wsb + 13140480);          // 512 B
  float*  wbq   = (float*)(wsb + 13140992);          // 1 KB
  float*  sbq   = (float*)(wsb + 13142016);          // 4 B

  k_prep  <<<64,   256, 0, stream>>>(dpos, W1, W2, posP, W1eSa, W1eSb, W2Sa, W2Sb);
  k_wprod <<<1028, 256, 0, stream>>>(Wk, Wv, Wq, W1, bk, bv, bq, WkqS, WvuS, bkq, bvu, wbq, sbq);
  k_dec   <<<NC / 8, 256, 0, stream>>>(df, (const float4*)WkqS, (const float4*)WvuS, bkq, bvu, wbq, sbq, Zd, Ud, bqK);
  k_knn   <<<NF / 8, 256, 0, stream>>>(epos, posP, knnI);
  k_amlp  <<<NF / 16, 256, 0, stream>>>(knnI, Zd, Ud, bqK, ef, W1eSa, W1eSb, b1, W2Sa, W2Sb, b2, lng, lnb, epos, lab, out);
  (void)in_sizes; (void)n_in; (void)out_size; (void)ws_size;
}

// Round 5
// 333.525 us; speedup vs baseline: 1.0821x; 1.0185x over previous
//
#include <hip/hip_runtime.h>
#include <hip/hip_bf16.h>

typedef __hip_bfloat16 bf16;
typedef unsigned short u16;
typedef float f32x2 __attribute__((ext_vector_type(2)));

#define NC 8192
#define NF 32768
#define KNN 16
#define FMAXV 3.402823466e+38f

__device__ __forceinline__ float bfbits2f(u16 u){
  union { unsigned u; float f; } x; x.u = ((unsigned)u) << 16; return x.f;
}
__device__ __forceinline__ float asfloat(unsigned u){
  union { unsigned u; float f; } x; x.u = u; return x.f;
}
// packed fp32 fma: d = a*b + c on both halves (IEEE fma per half, bit-exact vs fmaf)
__device__ __forceinline__ f32x2 pk_fma(f32x2 a, f32x2 b, f32x2 c){
  f32x2 d;
  asm("v_pk_fma_f32 %0, %1, %2, %3" : "=v"(d) : "v"(a), "v"(b), "v"(c));
  return d;
}

// ---------- k_pw: fused k_prep + k_wprod (1028 wprod blocks + 64 prep blocks = 1092) ----------
__global__ __launch_bounds__(256) void k_pw(const float* __restrict__ dpos,
                                            const float* __restrict__ W1,
                                            const float* __restrict__ W2,
                                            float4* __restrict__ posP,
                                            float4* __restrict__ W1eSa,
                                            float4* __restrict__ W1eSb,
                                            float4* __restrict__ W2Sa,
                                            float4* __restrict__ W2Sb,
                                            const float* __restrict__ Wk,
                                            const float* __restrict__ Wv,
                                            const float* __restrict__ Wq,
                                            const float* __restrict__ bk,
                                            const float* __restrict__ bv,
                                            const float* __restrict__ bq,
                                            float* __restrict__ WkqS,
                                            float* __restrict__ WvuS,
                                            float* __restrict__ bkq,
                                            float* __restrict__ bvu,
                                            float* __restrict__ wbq,
                                            float* __restrict__ sbq){
  __shared__ float partial[256];
  __shared__ float red[256];
  int gb = blockIdx.x, t = threadIdx.x;
  if (gb >= 1028){
    // ---- prep part ----
    int g = (gb - 1028) * 256 + t;
    if (g < 4096){
      const float2* dp2 = (const float2*)(dpos + (size_t)g * 6);
      float2 a = dp2[0], b = dp2[1], c = dp2[2];
      float x0 = a.x, y0 = a.y, z0 = b.x;
      float x1 = b.y, y1 = c.x, z1 = c.y;
      float dd0 = __fadd_rn(__fadd_rn(__fmul_rn(x0,x0), __fmul_rn(y0,y0)), __fmul_rn(z0,z0));
      float dd1 = __fadd_rn(__fadd_rn(__fmul_rn(x1,x1), __fmul_rn(y1,y1)), __fmul_rn(z1,z1));
      posP[g * 2]     = make_float4(x0, x1, y0, y1);
      posP[g * 2 + 1] = make_float4(z0, z1, dd0 * 0.5f, dd1 * 0.5f);
    } else if (g >= 8192 && g < 10240){
      int f = g - 8192; int c4 = f >> 6, jg = f & 63;
      W1eSa[f] = ((const float4*)(W1 + (size_t)(2 * jg) * 384 + 256))[c4];
    } else if (g >= 10240 && g < 12288){
      int f = g - 10240; int c4 = f >> 6, jg = f & 63;
      W1eSb[f] = ((const float4*)(W1 + (size_t)(2 * jg + 1) * 384 + 256))[c4];
    } else if (g >= 12288 && g < 14336){
      int f = g - 12288; int c4 = f >> 6, jg = f & 63;
      W2Sa[f] = ((const float4*)(W2 + (size_t)(2 * jg) * 128))[c4];
    } else if (g >= 14336 && g < 16384){
      int f = g - 14336; int c4 = f >> 6, jg = f & 63;
      W2Sb[f] = ((const float4*)(W2 + (size_t)(2 * jg + 1) * 128))[c4];
    }
    return;
  }
  // ---- wprod part (4-way K-split) ----
  int B = gb;
  int csel = B >> 2, tch = B & 3;
  int o = (t & 63) + tch * 64;
  int q = t >> 6;
  int j0 = q * 64;
  if (csel < 128){
    int c = csel;
    float acc = 0.f;
    for (int j = j0; j < j0 + 64; ++j)
      acc = fmaf(Wk[(size_t)j * 256 + o], Wq[(size_t)j * 128 + c], acc);
    partial[t] = acc;
    if (tch == 0) red[t] = bk[t] * Wq[(size_t)t * 128 + c];
    __syncthreads();
    if (t < 64){
      float a = partial[t] + partial[t + 64] + partial[t + 128] + partial[t + 192];
      WkqS[(size_t)((o >> 2) * 128 + c) * 4 + (o & 3)] = a;
    }
    if (tch == 0){
      for (int s = 128; s > 0; s >>= 1){ if (t < s) red[t] += red[t + s]; __syncthreads(); }
      if (t == 0) bkq[c] = red[0];
    }
  } else if (csel < 256){
    int h = csel - 128;
    float acc = 0.f;
    for (int j = j0; j < j0 + 64; ++j)
      acc = fmaf(Wv[(size_t)j * 256 + o], W1[(size_t)h * 384 + j], acc);
    partial[t] = acc;
    if (tch == 0) red[t] = bv[t] * W1[(size_t)h * 384 + t];
    __syncthreads();
    if (t < 64){
      float a = partial[t] + partial[t + 64] + partial[t + 128] + partial[t + 192];
      WvuS[(size_t)((o >> 2) * 128 + h) * 4 + (o & 3)] = a;
    }
    if (tch == 0){
      for (int s = 128; s > 0; s >>= 1){ if (t < s) red[t] += red[t + s]; __syncthreads(); }
      if (t == 0) bvu[h] = red[0];
    }
  } else {
    float acc = 0.f;
    for (int j = j0; j < j0 + 64; ++j)
      acc = fmaf(Wk[(size_t)j * 256 + o], bq[j], acc);
    partial[t] = acc;
    if (tch == 0) red[t] = bk[t] * bq[t];
    __syncthreads();
    if (t < 64){
      float a = partial[t] + partial[t + 64] + partial[t + 128] + partial[t + 192];
      wbq[o] = a;
    }
    if (tch == 0){
      for (int s = 128; s > 0; s >>= 1){ if (t < s) red[t] += red[t + s]; __syncthreads(); }
      if (t == 0) sbq[0] = red[0];
    }
  }
}

// ---------- k_dk: fused k_dec + k_knn, block-interleaved for CU co-residency ----------
// 5120 blocks: g%5==4 -> dec block g/5 (1024); else knn block (g/5)*4 + g%5 (4096).
// dec (memory/L2-bound) waves fill knn (VALU/latency-bound) stall slots on each CU.
__global__ __launch_bounds__(256) void k_dk(const float* __restrict__ df,
                                            const float4* __restrict__ WkqS,
                                            const float4* __restrict__ WvuS,
                                            const float* __restrict__ bkq,
                                            const float* __restrict__ bvu,
                                            const float* __restrict__ wbq,
                                            const float* __restrict__ sbq,
                                            bf16* __restrict__ Zd, bf16* __restrict__ Ud,
                                            float* __restrict__ bqK,
                                            const float* __restrict__ epos,
                                            const float4* __restrict__ posP,
                                            int* __restrict__ knnI){
  __shared__ float dpart[8][32];
  __shared__ float smin[8 * 64];
  __shared__ float tauLDS[8];
  __shared__ int   cnt[8];
  __shared__ float lval[8][64];
  __shared__ int   lidx[8][64];

  int g = blockIdx.x, t = threadIdx.x;
  int m = g % 5, q5 = g / 5;
  if (m == 4){
    // ================= dec path (block q5 of 1024) =================
    int g0 = q5 * 8;
    int half = __builtin_amdgcn_readfirstlane(t >> 7);
    int c = t & 127;
    const float4* W = half ? WvuS : WkqS;
    float acc[8];
    #pragma unroll
    for (int p = 0; p < 8; ++p) acc[p] = 0.f;
    for (int j4 = 0; j4 < 64; ++j4){
      float4 w = W[j4 * 128 + c];
      #pragma unroll
      for (int p = 0; p < 8; ++p){
        float4 a = ((const float4*)(df + (size_t)(g0 + p) * 256))[j4];
        acc[p] += w.x*a.x + w.y*a.y + w.z*a.z + w.w*a.w;
      }
    }
    float bias = half ? bvu[c] : bkq[c];
    bf16* dst = half ? Ud : Zd;
    #pragma unroll
    for (int p = 0; p < 8; ++p)
      dst[(size_t)(g0 + p) * 128 + c] = __float2bfloat16(acc[p] + bias);
    {
      int r = t >> 5, seg = t & 31;
      float s = 0.f;
      const float* dr = df + (size_t)(g0 + r) * 256 + seg * 8;
      const float* wq = wbq + seg * 8;
      #pragma unroll
      for (int e = 0; e < 8; ++e) s = fmaf(dr[e], wq[e], s);
      dpart[r][seg] = s;
    }
    __syncthreads();
    if (t < 8){
      float s = sbq[0];
      #pragma unroll
      for (int seg = 0; seg < 32; ++seg) s += dpart[t][seg];
      bqK[g0 + t] = s;
    }
    return;
  }

  // ================= knn path (block kb of 4096) =================
  int kb = q5 * 4 + m;
  int lane = t & 63, w = t >> 6;
  int n0 = kb * 8;
  f32x2 nex2[8], ney2[8], nez2[8];
  #pragma unroll
  for (int p = 0; p < 8; ++p){
    float nx = -epos[(n0 + p) * 3 + 0];
    float ny = -epos[(n0 + p) * 3 + 1];
    float nz = -epos[(n0 + p) * 3 + 2];
    nex2[p].x = nx; nex2[p].y = nx;
    ney2[p].x = ny; ney2[p].y = ny;
    nez2[p].x = nz; nez2[p].y = nz;
  }
  const float4* base = posP + w * 2048;   // wave's 1024 candidate-pairs = 2048 float4

  // PASS A: per-lane minima over 2 packed candidates/iter (3 pk_fma + 2 min per point)
  f32x2 vmin2[8];
  #pragma unroll
  for (int p = 0; p < 8; ++p){ vmin2[p].x = FMAXV; vmin2[p].y = FMAXV; }
  #pragma unroll 4
  for (int s = 0; s < 16; ++s){
    int q2 = (s * 64 + lane) * 2;
    float4 XY = base[q2], ZW = base[q2 + 1];
    f32x2 X = {XY.x, XY.y}, Y = {XY.z, XY.w}, Z = {ZW.x, ZW.y}, W = {ZW.z, ZW.w};
    #pragma unroll
    for (int p = 0; p < 8; ++p){
      f32x2 v2 = pk_fma(nex2[p], X, W);
      v2 = pk_fma(ney2[p], Y, v2);
      v2 = pk_fma(nez2[p], Z, v2);
      vmin2[p].x = fminf(vmin2[p].x, v2.x);
      vmin2[p].y = fminf(vmin2[p].y, v2.y);
    }
  }
  float vmin[8];
  #pragma unroll
  for (int p = 0; p < 8; ++p) vmin[p] = fminf(vmin2[p].x, vmin2[p].y);

  // full bitonic sort of 64 lane-minima, 8 point-registers at once (lanes 0..15 -> ascending top-16)
  #pragma unroll
  for (int k = 2; k <= 64; k <<= 1){
    #pragma unroll
    for (int j = k >> 1; j > 0; j >>= 1){
      bool keepmin = ((lane & j) == 0) == ((lane & k) == 0);
      #pragma unroll
      for (int p = 0; p < 8; ++p){
        float pv = __shfl_xor(vmin[p], j);
        vmin[p] = keepmin ? fminf(vmin[p], pv) : fmaxf(vmin[p], pv);
      }
    }
  }
  if (lane < 16){
    #pragma unroll
    for (int p = 0; p < 8; ++p) smin[p * 64 + w * 16 + lane] = vmin[p];
  }
  if (t < 8) cnt[t] = 0;
  __syncthreads();

  // union 17th-smallest for points 2w, 2w+1 (interleaved).
  // smin holds 4 ascending 16-runs per point; read odd groups reversed -> two bitonic-32s,
  // merge-32 (dir by bit5) then merge-64 ascending: 11 stages total. tau = lane 16.
  {
    int src = (lane & 16) ? (lane ^ 15) : lane;
    float v0 = smin[(w * 2 + 0) * 64 + src];
    float v1 = smin[(w * 2 + 1) * 64 + src];
    #pragma unroll
    for (int j = 16; j > 0; j >>= 1){
      bool keepmin = ((lane & 32) == 0) == ((lane & j) == 0);
      float p0 = __shfl_xor(v0, j); v0 = keepmin ? fminf(v0, p0) : fmaxf(v0, p0);
      float p1 = __shfl_xor(v1, j); v1 = keepmin ? fminf(v1, p1) : fmaxf(v1, p1);
    }
    #pragma unroll
    for (int j = 32; j > 0; j >>= 1){
      bool keepmin = ((lane & j) == 0);
      float p0 = __shfl_xor(v0, j); v0 = keepmin ? fminf(v0, p0) : fmaxf(v0, p0);
      float p1 = __shfl_xor(v1, j); v1 = keepmin ? fminf(v1, p1) : fmaxf(v1, p1);
    }
    if (lane == 16){ tauLDS[w * 2] = v0; tauLDS[w * 2 + 1] = v1; }
  }
  __syncthreads();
  float tau0[8];
  #pragma unroll
  for (int p = 0; p < 8; ++p) tau0[p] = tauLDS[p];

  // PASS B: filtered append (identical packed val expression)
  #pragma unroll 2
  for (int s = 0; s < 16; ++s){
    int q = s * 64 + lane;
    float4 XY = base[q * 2], ZW = base[q * 2 + 1];
    f32x2 X = {XY.x, XY.y}, Y = {XY.z, XY.w}, Z = {ZW.x, ZW.y}, W = {ZW.z, ZW.w};
    int cand0 = w * 2048 + q * 2;
    #pragma unroll
    for (int p = 0; p < 8; ++p){
      f32x2 v2 = pk_fma(nex2[p], X, W);
      v2 = pk_fma(ney2[p], Y, v2);
      v2 = pk_fma(nez2[p], Z, v2);
      if (v2.x <= tau0[p]){
        int slot = atomicAdd(&cnt[p], 1);
        if (slot < 64){ lval[p][slot] = v2.x; lidx[p][slot] = cand0; }
      }
      if (v2.y <= tau0[p]){
        int slot = atomicAdd(&cnt[p], 1);
        if (slot < 64){ lval[p][slot] = v2.y; lidx[p][slot] = cand0 + 1; }
      }
    }
  }
  __syncthreads();

  // finalize points 2w, 2w+1 interleaved: exact (val,idx) select-16, write indices
  {
    int p0 = w * 2, p1 = w * 2 + 1;
    int nA = n0 + p0, nB = n0 + p1;
    int c0 = cnt[p0]; if (c0 > 64) c0 = 64;
    int c1 = cnt[p1]; if (c1 > 64) c1 = 64;
    float va = (lane < c0) ? lval[p0][lane] : FMAXV;
    int   ia = (lane < c0) ? lidx[p0][lane] : 0x7fffffff;
    float vb = (lane < c1) ? lval[p1][lane] : FMAXV;
    int   ib = (lane < c1) ? lidx[p1][lane] : 0x7fffffff;

    // select-16 network: S1 sort 16-groups (alt dir by bit4), M1 min-merge xor16,
    // S2 resort bitonic-16 (dir by bit5), M2 min-merge xor32 -> exact top-16 in lanes 0..15
    #pragma unroll
    for (int k = 2; k <= 16; k <<= 1){
      #pragma unroll
      for (int j = k >> 1; j > 0; j >>= 1){
        bool keepmin = ((lane & k) == 0) == ((lane & j) == 0);
        { float pv = __shfl_xor(va, j); int pid = __shfl_xor(ia, j);
          bool pl = (pv < va) || (pv == va && pid < ia);
          if (keepmin ? pl : !pl){ va = pv; ia = pid; } }
        { float pv = __shfl_xor(vb, j); int pid = __shfl_xor(ib, j);
          bool pl = (pv < vb) || (pv == vb && pid < ib);
          if (keepmin ? pl : !pl){ vb = pv; ib = pid; } }
      }
    }
    { float pv = __shfl_xor(va, 16); int pid = __shfl_xor(ia, 16);
      if ((pv < va) || (pv == va && pid < ia)){ va = pv; ia = pid; } }
    { float pv = __shfl_xor(vb, 16); int pid = __shfl_xor(ib, 16);
      if ((pv < vb) || (pv == vb && pid < ib)){ vb = pv; ib = pid; } }
    #pragma unroll
    for (int j = 8; j > 0; j >>= 1){
      bool keepmin = ((lane & 32) == 0) == ((lane & j) == 0);
      { float pv = __shfl_xor(va, j); int pid = __shfl_xor(ia, j);
        bool pl = (pv < va) || (pv == va && pid < ia);
        if (keepmin ? pl : !pl){ va = pv; ia = pid; } }
      { float pv = __shfl_xor(vb, j); int pid = __shfl_xor(ib, j);
        bool pl = (pv < vb) || (pv == vb && pid < ib);
        if (keepmin ? pl : !pl){ vb = pv; ib = pid; } }
    }
    { float pv = __shfl_xor(va, 32); int pid = __shfl_xor(ia, 32);
      if ((pv < va) || (pv == va && pid < ia)){ va = pv; ia = pid; } }
    { float pv = __shfl_xor(vb, 32); int pid = __shfl_xor(ib, 32);
      if ((pv < vb) || (pv == vb && pid < ib)){ vb = pv; ib = pid; } }

    if (lane < 16){
      knnI[(size_t)nA * 16 + lane] = ia;
      knnI[(size_t)nB * 16 + lane] = ib;
    }
  }
}

// ---------- k_amlp: fused attention read-out + MLP + LN + tail ----------
// Phase 1 (attention): 16 lanes per point; lane kk owns neighbor kk. Full 128-dot per lane
// (no cross-lane reduce), softmax via 4-step shfl within the 16-group, agg gathers Ud rows
// fully coalesced (16 lanes x 16B = one 256B row), result -> haggL in LDS (fp32).
// Phase 2: h = relu(haggL + W1e@ef + b1); up = W2@h + b2; LN; out.
__global__ __launch_bounds__(256) void k_amlp(const int* __restrict__ knnI,
                                              const bf16* __restrict__ Zd,
                                              const bf16* __restrict__ Ud,
                                              const float* __restrict__ bqK,
                                              const float* __restrict__ ef,
                                              const float4* __restrict__ W1eSa,
                                              const float4* __restrict__ W1eSb,
                                              const float* __restrict__ b1,
                                              const float4* __restrict__ W2Sa,
                                              const float4* __restrict__ W2Sb,
                                              const float* __restrict__ b2,
                                              const float* __restrict__ lng, const float* __restrict__ lnb,
                                              const float* __restrict__ epos, const int* __restrict__ lab,
                                              float* __restrict__ out){
  __shared__ float haggL[16 * 128];
  __shared__ float hbuf[16 * 128];
  __shared__ float ubuf[16 * 128];
  __shared__ float stats[32];
  int t = threadIdx.x;
  int n0 = blockIdx.x * 16;
  int lane = t & 63, w = t >> 6;
  {
    int gid = blockIdx.x * 256 + t;
    if (gid < NF){
      float* op = out + (size_t)NF * 128;
      op[gid * 3 + 0] = epos[gid * 3 + 0];
      op[gid * 3 + 1] = epos[gid * 3 + 1];
      op[gid * 3 + 2] = epos[gid * 3 + 2];
      out[(size_t)NF * 128 + (size_t)NF * 3 + gid] = (float)lab[gid];
    }
  }

  // ---- attention phase: point pp = w*4 + (lane>>4), neighbor slot kk = lane&15 ----
  {
    int kk = lane & 15;
    int pp = w * 4 + (lane >> 4);
    int n = n0 + pp;
    int ik = knnI[(size_t)n * 16 + kk];
    const uint4*  zr = (const uint4*)((const u16*)Zd + (size_t)ik * 128);
    const float4* e4 = (const float4*)(ef + (size_t)n * 128);
    float pr = 0.f;
    #pragma unroll
    for (int i = 0; i < 16; ++i){
      uint4 z = zr[i];
      float4 ea = e4[2 * i], eb = e4[2 * i + 1];
      pr = fmaf(ea.x, asfloat(z.x << 16), pr); pr = fmaf(ea.y, asfloat(z.x & 0xffff0000u), pr);
      pr = fmaf(ea.z, asfloat(z.y << 16), pr); pr = fmaf(ea.w, asfloat(z.y & 0xffff0000u), pr);
      pr = fmaf(eb.x, asfloat(z.z << 16), pr); pr = fmaf(eb.y, asfloat(z.z & 0xffff0000u), pr);
      pr = fmaf(eb.z, asfloat(z.w << 16), pr); pr = fmaf(eb.w, asfloat(z.w & 0xffff0000u), pr);
    }
    float sc = (pr + bqK[ik]) * (1.0f / 16.0f);
    float mx = sc;
    #pragma unroll
    for (int off = 1; off < 16; off <<= 1) mx = fmaxf(mx, __shfl_xor(mx, off));
    float e = __expf(sc - mx);
    float l = e;
    #pragma unroll
    for (int off = 1; off < 16; off <<= 1) l += __shfl_xor(l, off);
    float wgt = e / l;

    float acc8[8];
    #pragma unroll
    for (int j = 0; j < 8; ++j) acc8[j] = 0.f;
    int gbase = lane & 48;
    #pragma unroll
    for (int k2 = 0; k2 < 16; ++k2){
      int src = gbase | k2;
      float wk = __shfl(wgt, src);
      int ikk = __shfl(ik, src);
      uint4 uu = *(const uint4*)((const u16*)Ud + (size_t)ikk * 128 + kk * 8);
      acc8[0] = fmaf(wk, asfloat(uu.x << 16), acc8[0]);
      acc8[1] = fmaf(wk, asfloat(uu.x & 0xffff0000u), acc8[1]);
      acc8[2] = fmaf(wk, asfloat(uu.y << 16), acc8[2]);
      acc8[3] = fmaf(wk, asfloat(uu.y & 0xffff0000u), acc8[3]);
      acc8[4] = fmaf(wk, asfloat(uu.z << 16), acc8[4]);
      acc8[5] = fmaf(wk, asfloat(uu.z & 0xffff0000u), acc8[5]);
      acc8[6] = fmaf(wk, asfloat(uu.w << 16), acc8[6]);
      acc8[7] = fmaf(wk, asfloat(uu.w & 0xffff0000u), acc8[7]);
    }
    float4* hp = (float4*)&haggL[pp * 128 + kk * 8];
    hp[0] = make_float4(acc8[0], acc8[1], acc8[2], acc8[3]);
    hp[1] = make_float4(acc8[4], acc8[5], acc8[6], acc8[7]);
  }

  // ---- MLP phase ----
  int jg = t & 63;
  int pg4 = __builtin_amdgcn_readfirstlane((t >> 6) * 4);
  int j0 = jg * 2;
  float acc[2][4];
  #pragma unroll
  for (int a = 0; a < 2; ++a)
    #pragma unroll
    for (int p = 0; p < 4; ++p) acc[a][p] = 0.f;
  for (int c4 = 0; c4 < 32; ++c4){
    float4 wa = W1eSa[c4 * 64 + jg];
    float4 wb = W1eSb[c4 * 64 + jg];
    #pragma unroll
    for (int p = 0; p < 4; ++p){
      float4 x = ((const float4*)(ef + (size_t)(n0 + pg4 + p) * 128))[c4];
      acc[0][p] += wa.x*x.x + wa.y*x.y + wa.z*x.z + wa.w*x.w;
      acc[1][p] += wb.x*x.x + wb.y*x.y + wb.z*x.z + wb.w*x.w;
    }
  }
  __syncthreads();   // haggL ready
  float b1a = b1[j0], b1b = b1[j0 + 1];
  #pragma unroll
  for (int p = 0; p < 4; ++p){
    float2 hgv = *(const float2*)&haggL[(pg4 + p) * 128 + j0];
    hbuf[(pg4 + p) * 128 + j0]     = fmaxf(acc[0][p] + b1a + hgv.x, 0.f);
    hbuf[(pg4 + p) * 128 + j0 + 1] = fmaxf(acc[1][p] + b1b + hgv.y, 0.f);
  }
  __syncthreads();
  float acc2[2][4];
  #pragma unroll
  for (int a = 0; a < 2; ++a)
    #pragma unroll
    for (int p = 0; p < 4; ++p) acc2[a][p] = 0.f;
  const float4* hb4 = (const float4*)hbuf;
  for (int c4 = 0; c4 < 32; ++c4){
    float4 wa = W2Sa[c4 * 64 + jg];
    float4 wb = W2Sb[c4 * 64 + jg];
    #pragma unroll
    for (int p = 0; p < 4; ++p){
      float4 x = hb4[(pg4 + p) * 32 + c4];
      acc2[0][p] += wa.x*x.x + wa.y*x.y + wa.z*x.z + wa.w*x.w;
      acc2[1][p] += wb.x*x.x + wb.y*x.y + wb.z*x.z + wb.w*x.w;
    }
  }
  float b2a = b2[j0], b2b = b2[j0 + 1];
  float u[2][4];
  #pragma unroll
  for (int p = 0; p < 4; ++p){
    u[0][p] = acc2[0][p] + b2a;
    u[1][p] = acc2[1][p] + b2b;
    ubuf[(pg4 + p) * 128 + j0]     = u[0][p];
    ubuf[(pg4 + p) * 128 + j0 + 1] = u[1][p];
  }
  __syncthreads();
  {
    int p = t >> 4, qi = t & 15;
    const float* ub = &ubuf[p * 128 + qi * 8];
    float s = 0.f, s2 = 0.f;
    #pragma unroll
    for (int e2i = 0; e2i < 8; ++e2i){ float v = ub[e2i]; s += v; s2 += v * v; }
    #pragma unroll
    for (int off = 1; off < 16; off <<= 1){ s += __shfl_xor(s, off); s2 += __shfl_xor(s2, off); }
    if (qi == 0){
      float mu = s * (1.f / 128.f);
      float var = s2 * (1.f / 128.f) - mu * mu;
      stats[p] = mu;
      stats[16 + p] = rsqrtf(fmaxf(var, 0.f) + 1e-5f);
    }
  }
  __syncthreads();
  float ga = lng[j0], gb = lng[j0 + 1];
  float ba = lnb[j0], bbv = lnb[j0 + 1];
  #pragma unroll
  for (int p = 0; p < 4; ++p){
    float mu = stats[pg4 + p], rs = stats[16 + pg4 + p];
    out[(size_t)(n0 + pg4 + p) * 128 + j0]     = (u[0][p] - mu) * rs * ga + ba;
    out[(size_t)(n0 + pg4 + p) * 128 + j0 + 1] = (u[1][p] - mu) * rs * gb + bbv;
  }
}

extern "C" void kernel_launch(void* const* d_in, const int* in_sizes, int n_in,
                              void* d_out, int out_size, void* d_ws, size_t ws_size,
                              hipStream_t stream){
  const float* df   = (const float*)d_in[0];
  const float* dpos = (const float*)d_in[1];
  const float* ef   = (const float*)d_in[2];
  const float* epos = (const float*)d_in[3];
  const int*   lab  = (const int*)d_in[4];
  const float* Wq = (const float*)d_in[5];
  const float* bq = (const float*)d_in[6];
  const float* Wk = (const float*)d_in[7];
  const float* bk = (const float*)d_in[8];
  const float* Wv = (const float*)d_in[9];
  const float* bv = (const float*)d_in[10];
  const float* W1 = (const float*)d_in[11];
  const float* b1 = (const float*)d_in[12];
  const float* W2 = (const float*)d_in[13];
  const float* b2 = (const float*)d_in[14];
  const float* lng = (const float*)d_in[15];
  const float* lnb = (const float*)d_in[16];
  float* out = (float*)d_out;

  // workspace layout (~13.2 MB)
  char* wsb = (char*)d_ws;
  float4* posP  = (float4*)(wsb);                    // 128 KB
  bf16*   Zd    = (bf16*)(wsb + 131072);             // 2 MB
  bf16*   Ud    = (bf16*)(wsb + 2228224);            // 2 MB
  float*  bqK   = (float*)(wsb + 4325376);           // 32 KB
  int*    knnI  = (int*)(wsb + 4358144);             // 2 MB (NF*16*4)
  float4* W1eSa = (float4*)(wsb + 12746752);         // 32 KB
  float4* W1eSb = (float4*)(wsb + 12779520);         // 32 KB
  float4* W2Sa  = (float4*)(wsb + 12812288);         // 32 KB
  float4* W2Sb  = (float4*)(wsb + 12845056);         // 32 KB
  float*  WkqS  = (float*)(wsb + 12877824);          // 128 KB
  float*  WvuS  = (float*)(wsb + 13008896);          // 128 KB
  float*  bkq   = (float*)(wsb + 13139968);          // 512 B
  float*  bvu   = (float*)(wsb + 13140480);          // 512 B
  float*  wbq   = (float*)(wsb + 13140992);          // 1 KB
  float*  sbq   = (float*)(wsb + 13142016);          // 4 B

  k_pw   <<<1092, 256, 0, stream>>>(dpos, W1, W2, posP, W1eSa, W1eSb, W2Sa, W2Sb,
                                    Wk, Wv, Wq, bk, bv, bq, WkqS, WvuS, bkq, bvu, wbq, sbq);
  k_dk   <<<5120, 256, 0, stream>>>(df, (const float4*)WkqS, (const float4*)WvuS, bkq, bvu, wbq, sbq,
                                    Zd, Ud, bqK, epos, posP, knnI);
  k_amlp <<<NF / 16, 256, 0, stream>>>(knnI, Zd, Ud, bqK, ef, W1eSa, W1eSb, b1, W2Sa, W2Sb, b2, lng, lnb, epos, lab, out);
  (void)in_sizes; (void)n_in; (void)out_size; (void)ws_size;
}

// Round 6
// 319.953 us; speedup vs baseline: 1.1280x; 1.0424x over previous
//
#include <hip/hip_runtime.h>
#include <hip/hip_bf16.h>

typedef __hip_bfloat16 bf16;
typedef unsigned short u16;
typedef float f32x2 __attribute__((ext_vector_type(2)));

#define NC 8192
#define NF 32768
#define KNN 16
#define FMAXV 3.402823466e+38f

__device__ __forceinline__ float bfbits2f(u16 u){
  union { unsigned u; float f; } x; x.u = ((unsigned)u) << 16; return x.f;
}
__device__ __forceinline__ float asfloat(unsigned u){
  union { unsigned u; float f; } x; x.u = u; return x.f;
}
// packed fp32 fma: d = a*b + c on both halves (IEEE fma per half, bit-exact vs fmaf)
__device__ __forceinline__ f32x2 pk_fma(f32x2 a, f32x2 b, f32x2 c){
  f32x2 d;
  asm("v_pk_fma_f32 %0, %1, %2, %3" : "=v"(d) : "v"(a), "v"(b), "v"(c));
  return d;
}

// ---------- k_pw: fused k_prep + k_wprod + output tail copy (1028 + 64 + 128 = 1220 blocks) ----------
__global__ __launch_bounds__(256) void k_pw(const float* __restrict__ dpos,
                                            const float* __restrict__ W1,
                                            const float* __restrict__ W2,
                                            float4* __restrict__ posP,
                                            float4* __restrict__ W1eSa,
                                            float4* __restrict__ W1eSb,
                                            float4* __restrict__ W2Sa,
                                            float4* __restrict__ W2Sb,
                                            const float* __restrict__ Wk,
                                            const float* __restrict__ Wv,
                                            const float* __restrict__ Wq,
                                            const float* __restrict__ bk,
                                            const float* __restrict__ bv,
                                            const float* __restrict__ bq,
                                            float* __restrict__ WkqS,
                                            float* __restrict__ WvuS,
                                            float* __restrict__ bkq,
                                            float* __restrict__ bvu,
                                            float* __restrict__ wbq,
                                            float* __restrict__ sbq,
                                            const float* __restrict__ epos,
                                            const int* __restrict__ lab,
                                            float* __restrict__ out){
  __shared__ float partial[256];
  __shared__ float red[256];
  int gb = blockIdx.x, t = threadIdx.x;
  if (gb >= 1092){
    // ---- output tail copy (epos + labels) ----
    int gid = (gb - 1092) * 256 + t;
    if (gid < NF){
      float* op = out + (size_t)NF * 128;
      op[gid * 3 + 0] = epos[gid * 3 + 0];
      op[gid * 3 + 1] = epos[gid * 3 + 1];
      op[gid * 3 + 2] = epos[gid * 3 + 2];
      out[(size_t)NF * 128 + (size_t)NF * 3 + gid] = (float)lab[gid];
    }
    return;
  }
  if (gb >= 1028){
    // ---- prep part ----
    int g = (gb - 1028) * 256 + t;
    if (g < 4096){
      const float2* dp2 = (const float2*)(dpos + (size_t)g * 6);
      float2 a = dp2[0], b = dp2[1], c = dp2[2];
      float x0 = a.x, y0 = a.y, z0 = b.x;
      float x1 = b.y, y1 = c.x, z1 = c.y;
      float dd0 = __fadd_rn(__fadd_rn(__fmul_rn(x0,x0), __fmul_rn(y0,y0)), __fmul_rn(z0,z0));
      float dd1 = __fadd_rn(__fadd_rn(__fmul_rn(x1,x1), __fmul_rn(y1,y1)), __fmul_rn(z1,z1));
      posP[g * 2]     = make_float4(x0, x1, y0, y1);
      posP[g * 2 + 1] = make_float4(z0, z1, dd0 * 0.5f, dd1 * 0.5f);
    } else if (g >= 8192 && g < 10240){
      int f = g - 8192; int c4 = f >> 6, jg = f & 63;
      W1eSa[f] = ((const float4*)(W1 + (size_t)(2 * jg) * 384 + 256))[c4];
    } else if (g >= 10240 && g < 12288){
      int f = g - 10240; int c4 = f >> 6, jg = f & 63;
      W1eSb[f] = ((const float4*)(W1 + (size_t)(2 * jg + 1) * 384 + 256))[c4];
    } else if (g >= 12288 && g < 14336){
      int f = g - 12288; int c4 = f >> 6, jg = f & 63;
      W2Sa[f] = ((const float4*)(W2 + (size_t)(2 * jg) * 128))[c4];
    } else if (g >= 14336 && g < 16384){
      int f = g - 14336; int c4 = f >> 6, jg = f & 63;
      W2Sb[f] = ((const float4*)(W2 + (size_t)(2 * jg + 1) * 128))[c4];
    }
    return;
  }
  // ---- wprod part (4-way K-split) ----
  int B = gb;
  int csel = B >> 2, tch = B & 3;
  int o = (t & 63) + tch * 64;
  int q = t >> 6;
  int j0 = q * 64;
  if (csel < 128){
    int c = csel;
    float acc = 0.f;
    for (int j = j0; j < j0 + 64; ++j)
      acc = fmaf(Wk[(size_t)j * 256 + o], Wq[(size_t)j * 128 + c], acc);
    partial[t] = acc;
    if (tch == 0) red[t] = bk[t] * Wq[(size_t)t * 128 + c];
    __syncthreads();
    if (t < 64){
      float a = partial[t] + partial[t + 64] + partial[t + 128] + partial[t + 192];
      WkqS[(size_t)((o >> 2) * 128 + c) * 4 + (o & 3)] = a;
    }
    if (tch == 0){
      for (int s = 128; s > 0; s >>= 1){ if (t < s) red[t] += red[t + s]; __syncthreads(); }
      if (t == 0) bkq[c] = red[0];
    }
  } else if (csel < 256){
    int h = csel - 128;
    float acc = 0.f;
    for (int j = j0; j < j0 + 64; ++j)
      acc = fmaf(Wv[(size_t)j * 256 + o], W1[(size_t)h * 384 + j], acc);
    partial[t] = acc;
    if (tch == 0) red[t] = bv[t] * W1[(size_t)h * 384 + t];
    __syncthreads();
    if (t < 64){
      float a = partial[t] + partial[t + 64] + partial[t + 128] + partial[t + 192];
      WvuS[(size_t)((o >> 2) * 128 + h) * 4 + (o & 3)] = a;
    }
    if (tch == 0){
      for (int s = 128; s > 0; s >>= 1){ if (t < s) red[t] += red[t + s]; __syncthreads(); }
      if (t == 0) bvu[h] = red[0];
    }
  } else {
    float acc = 0.f;
    for (int j = j0; j < j0 + 64; ++j)
      acc = fmaf(Wk[(size_t)j * 256 + o], bq[j], acc);
    partial[t] = acc;
    if (tch == 0) red[t] = bk[t] * bq[t];
    __syncthreads();
    if (t < 64){
      float a = partial[t] + partial[t + 64] + partial[t + 128] + partial[t + 192];
      wbq[o] = a;
    }
    if (tch == 0){
      for (int s = 128; s > 0; s >>= 1){ if (t < s) red[t] += red[t + s]; __syncthreads(); }
      if (t == 0) sbq[0] = red[0];
    }
  }
}

// ---------- k_dk: fused k_dec + k_knn, block-interleaved for CU co-residency ----------
// 5120 blocks: g%5==4 -> dec block g/5 (1024); else knn block (g/5)*4 + g%5 (4096).
// Pass B: ballot + prefix-popcount append into per-wave PRIVATE buffers (no atomics,
// wave-uniform skip branch). Selection set-identical to atomic version.
__global__ __launch_bounds__(256) void k_dk(const float* __restrict__ df,
                                            const float4* __restrict__ WkqS,
                                            const float4* __restrict__ WvuS,
                                            const float* __restrict__ bkq,
                                            const float* __restrict__ bvu,
                                            const float* __restrict__ wbq,
                                            const float* __restrict__ sbq,
                                            bf16* __restrict__ Zd, bf16* __restrict__ Ud,
                                            float* __restrict__ bqK,
                                            const float* __restrict__ epos,
                                            const float4* __restrict__ posP,
                                            int* __restrict__ knnI){
  __shared__ float dpart[8][32];
  __shared__ float smin[8 * 64];
  __shared__ float tauLDS[8];
  __shared__ int   cntL[8][4];
  __shared__ float lval[8][4][64];
  __shared__ int   lidx[8][4][64];

  int g = blockIdx.x, t = threadIdx.x;
  int m = g % 5, q5 = g / 5;
  if (m == 4){
    // ================= dec path (block q5 of 1024) =================
    int g0 = q5 * 8;
    int half = __builtin_amdgcn_readfirstlane(t >> 7);
    int c = t & 127;
    const float4* W = half ? WvuS : WkqS;
    float acc[8];
    #pragma unroll
    for (int p = 0; p < 8; ++p) acc[p] = 0.f;
    for (int j4 = 0; j4 < 64; ++j4){
      float4 w = W[j4 * 128 + c];
      #pragma unroll
      for (int p = 0; p < 8; ++p){
        float4 a = ((const float4*)(df + (size_t)(g0 + p) * 256))[j4];
        acc[p] += w.x*a.x + w.y*a.y + w.z*a.z + w.w*a.w;
      }
    }
    float bias = half ? bvu[c] : bkq[c];
    bf16* dst = half ? Ud : Zd;
    #pragma unroll
    for (int p = 0; p < 8; ++p)
      dst[(size_t)(g0 + p) * 128 + c] = __float2bfloat16(acc[p] + bias);
    {
      int r = t >> 5, seg = t & 31;
      float s = 0.f;
      const float* dr = df + (size_t)(g0 + r) * 256 + seg * 8;
      const float* wq = wbq + seg * 8;
      #pragma unroll
      for (int e = 0; e < 8; ++e) s = fmaf(dr[e], wq[e], s);
      dpart[r][seg] = s;
    }
    __syncthreads();
    if (t < 8){
      float s = sbq[0];
      #pragma unroll
      for (int seg = 0; seg < 32; ++seg) s += dpart[t][seg];
      bqK[g0 + t] = s;
    }
    return;
  }

  // ================= knn path (block kb of 4096) =================
  int kb = q5 * 4 + m;
  int lane = t & 63, w = t >> 6;
  int n0 = kb * 8;
  f32x2 nex2[8], ney2[8], nez2[8];
  #pragma unroll
  for (int p = 0; p < 8; ++p){
    float nx = -epos[(n0 + p) * 3 + 0];
    float ny = -epos[(n0 + p) * 3 + 1];
    float nz = -epos[(n0 + p) * 3 + 2];
    nex2[p].x = nx; nex2[p].y = nx;
    ney2[p].x = ny; ney2[p].y = ny;
    nez2[p].x = nz; nez2[p].y = nz;
  }
  const float4* base = posP + w * 2048;   // wave's 1024 candidate-pairs = 2048 float4

  // PASS A: per-lane minima over 2 packed candidates/iter (3 pk_fma + 2 min per point)
  f32x2 vmin2[8];
  #pragma unroll
  for (int p = 0; p < 8; ++p){ vmin2[p].x = FMAXV; vmin2[p].y = FMAXV; }
  #pragma unroll 4
  for (int s = 0; s < 16; ++s){
    int q2 = (s * 64 + lane) * 2;
    float4 XY = base[q2], ZW = base[q2 + 1];
    f32x2 X = {XY.x, XY.y}, Y = {XY.z, XY.w}, Z = {ZW.x, ZW.y}, W = {ZW.z, ZW.w};
    #pragma unroll
    for (int p = 0; p < 8; ++p){
      f32x2 v2 = pk_fma(nex2[p], X, W);
      v2 = pk_fma(ney2[p], Y, v2);
      v2 = pk_fma(nez2[p], Z, v2);
      vmin2[p].x = fminf(vmin2[p].x, v2.x);
      vmin2[p].y = fminf(vmin2[p].y, v2.y);
    }
  }
  float vmin[8];
  #pragma unroll
  for (int p = 0; p < 8; ++p) vmin[p] = fminf(vmin2[p].x, vmin2[p].y);

  // full bitonic sort of 64 lane-minima, 8 point-registers at once (lanes 0..15 -> ascending top-16)
  #pragma unroll
  for (int k = 2; k <= 64; k <<= 1){
    #pragma unroll
    for (int j = k >> 1; j > 0; j >>= 1){
      bool keepmin = ((lane & j) == 0) == ((lane & k) == 0);
      #pragma unroll
      for (int p = 0; p < 8; ++p){
        float pv = __shfl_xor(vmin[p], j);
        vmin[p] = keepmin ? fminf(vmin[p], pv) : fmaxf(vmin[p], pv);
      }
    }
  }
  if (lane < 16){
    #pragma unroll
    for (int p = 0; p < 8; ++p) smin[p * 64 + w * 16 + lane] = vmin[p];
  }
  __syncthreads();

  // union 17th-smallest for points 2w, 2w+1 (interleaved).
  // smin holds 4 ascending 16-runs per point; read odd groups reversed -> two bitonic-32s,
  // merge-32 (dir by bit5) then merge-64 ascending: 11 stages total. tau = lane 16.
  {
    int src = (lane & 16) ? (lane ^ 15) : lane;
    float v0 = smin[(w * 2 + 0) * 64 + src];
    float v1 = smin[(w * 2 + 1) * 64 + src];
    #pragma unroll
    for (int j = 16; j > 0; j >>= 1){
      bool keepmin = ((lane & 32) == 0) == ((lane & j) == 0);
      float p0 = __shfl_xor(v0, j); v0 = keepmin ? fminf(v0, p0) : fmaxf(v0, p0);
      float p1 = __shfl_xor(v1, j); v1 = keepmin ? fminf(v1, p1) : fmaxf(v1, p1);
    }
    #pragma unroll
    for (int j = 32; j > 0; j >>= 1){
      bool keepmin = ((lane & j) == 0);
      float p0 = __shfl_xor(v0, j); v0 = keepmin ? fminf(v0, p0) : fmaxf(v0, p0);
      float p1 = __shfl_xor(v1, j); v1 = keepmin ? fminf(v1, p1) : fmaxf(v1, p1);
    }
    if (lane == 16){ tauLDS[w * 2] = v0; tauLDS[w * 2 + 1] = v1; }
  }
  __syncthreads();
  float tau0[8];
  #pragma unroll
  for (int p = 0; p < 8; ++p) tau0[p] = tauLDS[p];

  // PASS B: ballot + prefix-popcount append into per-wave private buffers
  unsigned long long lmlt = (1ull << lane) - 1ull;
  int cnt[8] = {0,0,0,0,0,0,0,0};
  #pragma unroll 2
  for (int s = 0; s < 16; ++s){
    int q = s * 64 + lane;
    float4 XY = base[q * 2], ZW = base[q * 2 + 1];
    f32x2 X = {XY.x, XY.y}, Y = {XY.z, XY.w}, Z = {ZW.x, ZW.y}, W = {ZW.z, ZW.w};
    int cand0 = w * 2048 + q * 2;
    #pragma unroll
    for (int p = 0; p < 8; ++p){
      f32x2 v2 = pk_fma(nex2[p], X, W);
      v2 = pk_fma(ney2[p], Y, v2);
      v2 = pk_fma(nez2[p], Z, v2);
      bool h0 = v2.x <= tau0[p];
      bool h1 = v2.y <= tau0[p];
      unsigned long long m0 = __ballot(h0);
      unsigned long long m1 = __ballot(h1);
      if (m0 | m1){   // wave-uniform skip
        int base0 = cnt[p];
        int c0 = (int)__popcll(m0);
        if (h0){
          int s0 = base0 + (int)__popcll(m0 & lmlt);
          if (s0 < 64){ lval[p][w][s0] = v2.x; lidx[p][w][s0] = cand0; }
        }
        if (h1){
          int s1 = base0 + c0 + (int)__popcll(m1 & lmlt);
          if (s1 < 64){ lval[p][w][s1] = v2.y; lidx[p][w][s1] = cand0 + 1; }
        }
        cnt[p] = base0 + c0 + (int)__popcll(m1);
      }
    }
  }
  if (lane == 0){
    #pragma unroll
    for (int p = 0; p < 8; ++p) cntL[p][w] = (cnt[p] > 64) ? 64 : cnt[p];
  }
  __syncthreads();

  // finalize points 2w, 2w+1 interleaved: gather from 4 private segments, exact select-16
  {
    int p0 = w * 2, p1 = w * 2 + 1;
    int nA = n0 + p0, nB = n0 + p1;
    int cA0 = cntL[p0][0], cA1 = cntL[p0][1], cA2 = cntL[p0][2], cA3 = cntL[p0][3];
    int cB0 = cntL[p1][0], cB1 = cntL[p1][1], cB2 = cntL[p1][2], cB3 = cntL[p1][3];
    int oA1 = cA0, oA2 = oA1 + cA1, oA3 = oA2 + cA2; int totA = oA3 + cA3; if (totA > 64) totA = 64;
    int oB1 = cB0, oB2 = oB1 + cB1, oB3 = oB2 + cB2; int totB = oB3 + cB3; if (totB > 64) totB = 64;
    int segA = (lane >= oA1) + (lane >= oA2) + (lane >= oA3);
    int segB = (lane >= oB1) + (lane >= oB2) + (lane >= oB3);
    int basA = segA == 0 ? 0 : (segA == 1 ? oA1 : (segA == 2 ? oA2 : oA3));
    int basB = segB == 0 ? 0 : (segB == 1 ? oB1 : (segB == 2 ? oB2 : oB3));
    float va = (lane < totA) ? lval[p0][segA][lane - basA] : FMAXV;
    int   ia = (lane < totA) ? lidx[p0][segA][lane - basA] : 0x7fffffff;
    float vb = (lane < totB) ? lval[p1][segB][lane - basB] : FMAXV;
    int   ib = (lane < totB) ? lidx[p1][segB][lane - basB] : 0x7fffffff;

    // select-16 network: S1 sort 16-groups (alt dir by bit4), M1 min-merge xor16,
    // S2 resort bitonic-16 (dir by bit5), M2 min-merge xor32 -> exact top-16 in lanes 0..15
    #pragma unroll
    for (int k = 2; k <= 16; k <<= 1){
      #pragma unroll
      for (int j = k >> 1; j > 0; j >>= 1){
        bool keepmin = ((lane & k) == 0) == ((lane & j) == 0);
        { float pv = __shfl_xor(va, j); int pid = __shfl_xor(ia, j);
          bool pl = (pv < va) || (pv == va && pid < ia);
          if (keepmin ? pl : !pl){ va = pv; ia = pid; } }
        { float pv = __shfl_xor(vb, j); int pid = __shfl_xor(ib, j);
          bool pl = (pv < vb) || (pv == vb && pid < ib);
          if (keepmin ? pl : !pl){ vb = pv; ib = pid; } }
      }
    }
    { float pv = __shfl_xor(va, 16); int pid = __shfl_xor(ia, 16);
      if ((pv < va) || (pv == va && pid < ia)){ va = pv; ia = pid; } }
    { float pv = __shfl_xor(vb, 16); int pid = __shfl_xor(ib, 16);
      if ((pv < vb) || (pv == vb && pid < ib)){ vb = pv; ib = pid; } }
    #pragma unroll
    for (int j = 8; j > 0; j >>= 1){
      bool keepmin = ((lane & 32) == 0) == ((lane & j) == 0);
      { float pv = __shfl_xor(va, j); int pid = __shfl_xor(ia, j);
        bool pl = (pv < va) || (pv == va && pid < ia);
        if (keepmin ? pl : !pl){ va = pv; ia = pid; } }
      { float pv = __shfl_xor(vb, j); int pid = __shfl_xor(ib, j);
        bool pl = (pv < vb) || (pv == vb && pid < ib);
        if (keepmin ? pl : !pl){ vb = pv; ib = pid; } }
    }
    { float pv = __shfl_xor(va, 32); int pid = __shfl_xor(ia, 32);
      if ((pv < va) || (pv == va && pid < ia)){ va = pv; ia = pid; } }
    { float pv = __shfl_xor(vb, 32); int pid = __shfl_xor(ib, 32);
      if ((pv < vb) || (pv == vb && pid < ib)){ vb = pv; ib = pid; } }

    if (lane < 16){
      knnI[(size_t)nA * 16 + lane] = ia;
      knnI[(size_t)nB * 16 + lane] = ib;
    }
  }
}

// ---------- k_amlp: fused attention read-out + MLP + LN ----------
// Attention: 16 lanes per point; lane kk owns neighbor kk. Batched 8-deep prefetch of Zd
// rows; all 16 wgt/ik shfls pre-broadcast, Ud gathers batched 8-deep. Result -> haggL (LDS).
// MLP: unroll-4 on both c4 loops for load-ahead ILP.
__global__ __launch_bounds__(256) void k_amlp(const int* __restrict__ knnI,
                                              const bf16* __restrict__ Zd,
                                              const bf16* __restrict__ Ud,
                                              const float* __restrict__ bqK,
                                              const float* __restrict__ ef,
                                              const float4* __restrict__ W1eSa,
                                              const float4* __restrict__ W1eSb,
                                              const float* __restrict__ b1,
                                              const float4* __restrict__ W2Sa,
                                              const float4* __restrict__ W2Sb,
                                              const float* __restrict__ b2,
                                              const float* __restrict__ lng, const float* __restrict__ lnb,
                                              float* __restrict__ out){
  __shared__ float haggL[16 * 128];
  __shared__ float hbuf[16 * 128];
  __shared__ float ubuf[16 * 128];
  __shared__ float stats[32];
  int t = threadIdx.x;
  int n0 = blockIdx.x * 16;
  int lane = t & 63, w = t >> 6;

  // ---- attention phase: point pp = w*4 + (lane>>4), neighbor slot kk = lane&15 ----
  {
    int kk = lane & 15;
    int pp = w * 4 + (lane >> 4);
    int n = n0 + pp;
    int ik = knnI[(size_t)n * 16 + kk];
    float bz = bqK[ik];
    const uint4*  zr = (const uint4*)((const u16*)Zd + (size_t)ik * 128);
    const float4* e4 = (const float4*)(ef + (size_t)n * 128);
    float pr = 0.f;
    {
      uint4 zb[8];
      #pragma unroll
      for (int i = 0; i < 8; ++i) zb[i] = zr[i];
      #pragma unroll
      for (int i = 0; i < 8; ++i){
        uint4 z = zb[i];
        float4 ea = e4[2 * i], eb = e4[2 * i + 1];
        pr = fmaf(ea.x, asfloat(z.x << 16), pr); pr = fmaf(ea.y, asfloat(z.x & 0xffff0000u), pr);
        pr = fmaf(ea.z, asfloat(z.y << 16), pr); pr = fmaf(ea.w, asfloat(z.y & 0xffff0000u), pr);
        pr = fmaf(eb.x, asfloat(z.z << 16), pr); pr = fmaf(eb.y, asfloat(z.z & 0xffff0000u), pr);
        pr = fmaf(eb.z, asfloat(z.w << 16), pr); pr = fmaf(eb.w, asfloat(z.w & 0xffff0000u), pr);
      }
      #pragma unroll
      for (int i = 0; i < 8; ++i) zb[i] = zr[8 + i];
      #pragma unroll
      for (int i = 0; i < 8; ++i){
        uint4 z = zb[i];
        float4 ea = e4[2 * (8 + i)], eb = e4[2 * (8 + i) + 1];
        pr = fmaf(ea.x, asfloat(z.x << 16), pr); pr = fmaf(ea.y, asfloat(z.x & 0xffff0000u), pr);
        pr = fmaf(ea.z, asfloat(z.y << 16), pr); pr = fmaf(ea.w, asfloat(z.y & 0xffff0000u), pr);
        pr = fmaf(eb.x, asfloat(z.z << 16), pr); pr = fmaf(eb.y, asfloat(z.z & 0xffff0000u), pr);
        pr = fmaf(eb.z, asfloat(z.w << 16), pr); pr = fmaf(eb.w, asfloat(z.w & 0xffff0000u), pr);
      }
    }
    float sc = (pr + bz) * (1.0f / 16.0f);
    float mx = sc;
    #pragma unroll
    for (int off = 1; off < 16; off <<= 1) mx = fmaxf(mx, __shfl_xor(mx, off));
    float e = __expf(sc - mx);
    float l = e;
    #pragma unroll
    for (int off = 1; off < 16; off <<= 1) l += __shfl_xor(l, off);
    float wgt = e / l;

    // pre-broadcast all weights/indices, then batched gathers
    int gbase = lane & 48;
    float wk[16]; int ikk[16];
    #pragma unroll
    for (int k2 = 0; k2 < 16; ++k2){
      wk[k2]  = __shfl(wgt, gbase | k2);
      ikk[k2] = __shfl(ik,  gbase | k2);
    }
    float acc8[8];
    #pragma unroll
    for (int j = 0; j < 8; ++j) acc8[j] = 0.f;
    {
      uint4 ub[8];
      #pragma unroll
      for (int k2 = 0; k2 < 8; ++k2) ub[k2] = *(const uint4*)((const u16*)Ud + (size_t)ikk[k2] * 128 + kk * 8);
      #pragma unroll
      for (int k2 = 0; k2 < 8; ++k2){
        uint4 uu = ub[k2]; float wv = wk[k2];
        acc8[0] = fmaf(wv, asfloat(uu.x << 16), acc8[0]);
        acc8[1] = fmaf(wv, asfloat(uu.x & 0xffff0000u), acc8[1]);
        acc8[2] = fmaf(wv, asfloat(uu.y << 16), acc8[2]);
        acc8[3] = fmaf(wv, asfloat(uu.y & 0xffff0000u), acc8[3]);
        acc8[4] = fmaf(wv, asfloat(uu.z << 16), acc8[4]);
        acc8[5] = fmaf(wv, asfloat(uu.z & 0xffff0000u), acc8[5]);
        acc8[6] = fmaf(wv, asfloat(uu.w << 16), acc8[6]);
        acc8[7] = fmaf(wv, asfloat(uu.w & 0xffff0000u), acc8[7]);
      }
      #pragma unroll
      for (int k2 = 0; k2 < 8; ++k2) ub[k2] = *(const uint4*)((const u16*)Ud + (size_t)ikk[8 + k2] * 128 + kk * 8);
      #pragma unroll
      for (int k2 = 0; k2 < 8; ++k2){
        uint4 uu = ub[k2]; float wv = wk[8 + k2];
        acc8[0] = fmaf(wv, asfloat(uu.x << 16), acc8[0]);
        acc8[1] = fmaf(wv, asfloat(uu.x & 0xffff0000u), acc8[1]);
        acc8[2] = fmaf(wv, asfloat(uu.y << 16), acc8[2]);
        acc8[3] = fmaf(wv, asfloat(uu.y & 0xffff0000u), acc8[3]);
        acc8[4] = fmaf(wv, asfloat(uu.z << 16), acc8[4]);
        acc8[5] = fmaf(wv, asfloat(uu.z & 0xffff0000u), acc8[5]);
        acc8[6] = fmaf(wv, asfloat(uu.w << 16), acc8[6]);
        acc8[7] = fmaf(wv, asfloat(uu.w & 0xffff0000u), acc8[7]);
      }
    }
    float4* hp = (float4*)&haggL[pp * 128 + kk * 8];
    hp[0] = make_float4(acc8[0], acc8[1], acc8[2], acc8[3]);
    hp[1] = make_float4(acc8[4], acc8[5], acc8[6], acc8[7]);
  }

  // ---- MLP phase ----
  int jg = t & 63;
  int pg4 = __builtin_amdgcn_readfirstlane((t >> 6) * 4);
  int j0 = jg * 2;
  float acc[2][4];
  #pragma unroll
  for (int a = 0; a < 2; ++a)
    #pragma unroll
    for (int p = 0; p < 4; ++p) acc[a][p] = 0.f;
  #pragma unroll 4
  for (int c4 = 0; c4 < 32; ++c4){
    float4 wa = W1eSa[c4 * 64 + jg];
    float4 wb = W1eSb[c4 * 64 + jg];
    #pragma unroll
    for (int p = 0; p < 4; ++p){
      float4 x = ((const float4*)(ef + (size_t)(n0 + pg4 + p) * 128))[c4];
      acc[0][p] += wa.x*x.x + wa.y*x.y + wa.z*x.z + wa.w*x.w;
      acc[1][p] += wb.x*x.x + wb.y*x.y + wb.z*x.z + wb.w*x.w;
    }
  }
  __syncthreads();   // haggL ready
  float b1a = b1[j0], b1b = b1[j0 + 1];
  #pragma unroll
  for (int p = 0; p < 4; ++p){
    float2 hgv = *(const float2*)&haggL[(pg4 + p) * 128 + j0];
    hbuf[(pg4 + p) * 128 + j0]     = fmaxf(acc[0][p] + b1a + hgv.x, 0.f);
    hbuf[(pg4 + p) * 128 + j0 + 1] = fmaxf(acc[1][p] + b1b + hgv.y, 0.f);
  }
  __syncthreads();
  float acc2[2][4];
  #pragma unroll
  for (int a = 0; a < 2; ++a)
    #pragma unroll
    for (int p = 0; p < 4; ++p) acc2[a][p] = 0.f;
  const float4* hb4 = (const float4*)hbuf;
  #pragma unroll 4
  for (int c4 = 0; c4 < 32; ++c4){
    float4 wa = W2Sa[c4 * 64 + jg];
    float4 wb = W2Sb[c4 * 64 + jg];
    #pragma unroll
    for (int p = 0; p < 4; ++p){
      float4 x = hb4[(pg4 + p) * 32 + c4];
      acc2[0][p] += wa.x*x.x + wa.y*x.y + wa.z*x.z + wa.w*x.w;
      acc2[1][p] += wb.x*x.x + wb.y*x.y + wb.z*x.z + wb.w*x.w;
    }
  }
  float b2a = b2[j0], b2b = b2[j0 + 1];
  float u[2][4];
  #pragma unroll
  for (int p = 0; p < 4; ++p){
    u[0][p] = acc2[0][p] + b2a;
    u[1][p] = acc2[1][p] + b2b;
    ubuf[(pg4 + p) * 128 + j0]     = u[0][p];
    ubuf[(pg4 + p) * 128 + j0 + 1] = u[1][p];
  }
  __syncthreads();
  {
    int p = t >> 4, qi = t & 15;
    const float* ub = &ubuf[p * 128 + qi * 8];
    float s = 0.f, s2 = 0.f;
    #pragma unroll
    for (int e2i = 0; e2i < 8; ++e2i){ float v = ub[e2i]; s += v; s2 += v * v; }
    #pragma unroll
    for (int off = 1; off < 16; off <<= 1){ s += __shfl_xor(s, off); s2 += __shfl_xor(s2, off); }
    if (qi == 0){
      float mu = s * (1.f / 128.f);
      float var = s2 * (1.f / 128.f) - mu * mu;
      stats[p] = mu;
      stats[16 + p] = rsqrtf(fmaxf(var, 0.f) + 1e-5f);
    }
  }
  __syncthreads();
  float ga = lng[j0], gb = lng[j0 + 1];
  float ba = lnb[j0], bbv = lnb[j0 + 1];
  #pragma unroll
  for (int p = 0; p < 4; ++p){
    float mu = stats[pg4 + p], rs = stats[16 + pg4 + p];
    out[(size_t)(n0 + pg4 + p) * 128 + j0]     = (u[0][p] - mu) * rs * ga + ba;
    out[(size_t)(n0 + pg4 + p) * 128 + j0 + 1] = (u[1][p] - mu) * rs * gb + bbv;
  }
}

extern "C" void kernel_launch(void* const* d_in, const int* in_sizes, int n_in,
                              void* d_out, int out_size, void* d_ws, size_t ws_size,
                              hipStream_t stream){
  const float* df   = (const float*)d_in[0];
  const float* dpos = (const float*)d_in[1];
  const float* ef   = (const float*)d_in[2];
  const float* epos = (const float*)d_in[3];
  const int*   lab  = (const int*)d_in[4];
  const float* Wq = (const float*)d_in[5];
  const float* bq = (const float*)d_in[6];
  const float* Wk = (const float*)d_in[7];
  const float* bk = (const float*)d_in[8];
  const float* Wv = (const float*)d_in[9];
  const float* bv = (const float*)d_in[10];
  const float* W1 = (const float*)d_in[11];
  const float* b1 = (const float*)d_in[12];
  const float* W2 = (const float*)d_in[13];
  const float* b2 = (const float*)d_in[14];
  const float* lng = (const float*)d_in[15];
  const float* lnb = (const float*)d_in[16];
  float* out = (float*)d_out;

  // workspace layout (~13.2 MB)
  char* wsb = (char*)d_ws;
  float4* posP  = (float4*)(wsb);                    // 128 KB
  bf16*   Zd    = (bf16*)(wsb + 131072);             // 2 MB
  bf16*   Ud    = (bf16*)(wsb + 2228224);            // 2 MB
  float*  bqK   = (float*)(wsb + 4325376);           // 32 KB
  int*    knnI  = (int*)(wsb + 4358144);             // 2 MB (NF*16*4)
  float4* W1eSa = (float4*)(wsb + 12746752);         // 32 KB
  float4* W1eSb = (float4*)(wsb + 12779520);         // 32 KB
  float4* W2Sa  = (float4*)(wsb + 12812288);         // 32 KB
  float4* W2Sb  = (float4*)(wsb + 12845056);         // 32 KB
  float*  WkqS  = (float*)(wsb + 12877824);          // 128 KB
  float*  WvuS  = (float*)(wsb + 13008896);          // 128 KB
  float*  bkq   = (float*)(wsb + 13139968);          // 512 B
  float*  bvu   = (float*)(wsb + 13140480);          // 512 B
  float*  wbq   = (float*)(wsb + 13140992);          // 1 KB
  float*  sbq   = (float*)(wsb + 13142016);          // 4 B

  k_pw   <<<1220, 256, 0, stream>>>(dpos, W1, W2, posP, W1eSa, W1eSb, W2Sa, W2Sb,
                                    Wk, Wv, Wq, bk, bv, bq, WkqS, WvuS, bkq, bvu, wbq, sbq,
                                    epos, lab, out);
  k_dk   <<<5120, 256, 0, stream>>>(df, (const float4*)WkqS, (const float4*)WvuS, bkq, bvu, wbq, sbq,
                                    Zd, Ud, bqK, epos, posP, knnI);
  k_amlp <<<NF / 16, 256, 0, stream>>>(knnI, Zd, Ud, bqK, ef, W1eSa, W1eSb, b1, W2Sa, W2Sb, b2, lng, lnb, out);
  (void)in_sizes; (void)n_in; (void)out_size; (void)ws_size;
}

// Round 8
// 302.616 us; speedup vs baseline: 1.1927x; 1.0573x over previous
//
#include <hip/hip_runtime.h>
#include <hip/hip_bf16.h>

typedef __hip_bfloat16 bf16;
typedef unsigned short u16;
typedef float f32x2 __attribute__((ext_vector_type(2)));

#define NC 8192
#define NF 32768
#define KNN 16
#define FMAXV 3.402823466e+38f

__device__ __forceinline__ float bfbits2f(u16 u){
  union { unsigned u; float f; } x; x.u = ((unsigned)u) << 16; return x.f;
}
__device__ __forceinline__ float asfloat(unsigned u){
  union { unsigned u; float f; } x; x.u = u; return x.f;
}
// packed fp32 fma: d = a*b + c on both halves (IEEE fma per half, bit-exact vs fmaf)
__device__ __forceinline__ f32x2 pk_fma(f32x2 a, f32x2 b, f32x2 c){
  f32x2 d;
  asm("v_pk_fma_f32 %0, %1, %2, %3" : "=v"(d) : "v"(a), "v"(b), "v"(c));
  return d;
}

// ---------- k_pw: fused k_prep + k_wprod + output tail copy (1028 + 64 + 128 = 1220 blocks) ----------
__global__ __launch_bounds__(256) void k_pw(const float* __restrict__ dpos,
                                            const float* __restrict__ W1,
                                            const float* __restrict__ W2,
                                            float4* __restrict__ posP,
                                            float4* __restrict__ W1eSa,
                                            float4* __restrict__ W1eSb,
                                            float4* __restrict__ W2Sa,
                                            float4* __restrict__ W2Sb,
                                            const float* __restrict__ Wk,
                                            const float* __restrict__ Wv,
                                            const float* __restrict__ Wq,
                                            const float* __restrict__ bk,
                                            const float* __restrict__ bv,
                                            const float* __restrict__ bq,
                                            float* __restrict__ WkqS,
                                            float* __restrict__ WvuS,
                                            float* __restrict__ bkq,
                                            float* __restrict__ bvu,
                                            float* __restrict__ wbq,
                                            float* __restrict__ sbq,
                                            const float* __restrict__ epos,
                                            const int* __restrict__ lab,
                                            float* __restrict__ out){
  __shared__ float partial[256];
  __shared__ float red[256];
  int gb = blockIdx.x, t = threadIdx.x;
  if (gb >= 1092){
    // ---- output tail copy (epos + labels) ----
    int gid = (gb - 1092) * 256 + t;
    if (gid < NF){
      float* op = out + (size_t)NF * 128;
      op[gid * 3 + 0] = epos[gid * 3 + 0];
      op[gid * 3 + 1] = epos[gid * 3 + 1];
      op[gid * 3 + 2] = epos[gid * 3 + 2];
      out[(size_t)NF * 128 + (size_t)NF * 3 + gid] = (float)lab[gid];
    }
    return;
  }
  if (gb >= 1028){
    // ---- prep part ----
    int g = (gb - 1028) * 256 + t;
    if (g < 4096){
      const float2* dp2 = (const float2*)(dpos + (size_t)g * 6);
      float2 a = dp2[0], b = dp2[1], c = dp2[2];
      float x0 = a.x, y0 = a.y, z0 = b.x;
      float x1 = b.y, y1 = c.x, z1 = c.y;
      float dd0 = __fadd_rn(__fadd_rn(__fmul_rn(x0,x0), __fmul_rn(y0,y0)), __fmul_rn(z0,z0));
      float dd1 = __fadd_rn(__fadd_rn(__fmul_rn(x1,x1), __fmul_rn(y1,y1)), __fmul_rn(z1,z1));
      posP[g * 2]     = make_float4(x0, x1, y0, y1);
      posP[g * 2 + 1] = make_float4(z0, z1, dd0 * 0.5f, dd1 * 0.5f);
    } else if (g >= 8192 && g < 10240){
      int f = g - 8192; int c4 = f >> 6, jg = f & 63;
      W1eSa[f] = ((const float4*)(W1 + (size_t)(2 * jg) * 384 + 256))[c4];
    } else if (g >= 10240 && g < 12288){
      int f = g - 10240; int c4 = f >> 6, jg = f & 63;
      W1eSb[f] = ((const float4*)(W1 + (size_t)(2 * jg + 1) * 384 + 256))[c4];
    } else if (g >= 12288 && g < 14336){
      int f = g - 12288; int c4 = f >> 6, jg = f & 63;
      W2Sa[f] = ((const float4*)(W2 + (size_t)(2 * jg) * 128))[c4];
    } else if (g >= 14336 && g < 16384){
      int f = g - 14336; int c4 = f >> 6, jg = f & 63;
      W2Sb[f] = ((const float4*)(W2 + (size_t)(2 * jg + 1) * 128))[c4];
    }
    return;
  }
  // ---- wprod part (4-way K-split) ----
  int B = gb;
  int csel = B >> 2, tch = B & 3;
  int o = (t & 63) + tch * 64;
  int q = t >> 6;
  int j0 = q * 64;
  if (csel < 128){
    int c = csel;
    float acc = 0.f;
    for (int j = j0; j < j0 + 64; ++j)
      acc = fmaf(Wk[(size_t)j * 256 + o], Wq[(size_t)j * 128 + c], acc);
    partial[t] = acc;
    if (tch == 0) red[t] = bk[t] * Wq[(size_t)t * 128 + c];
    __syncthreads();
    if (t < 64){
      float a = partial[t] + partial[t + 64] + partial[t + 128] + partial[t + 192];
      WkqS[(size_t)((o >> 2) * 128 + c) * 4 + (o & 3)] = a;
    }
    if (tch == 0){
      for (int s = 128; s > 0; s >>= 1){ if (t < s) red[t] += red[t + s]; __syncthreads(); }
      if (t == 0) bkq[c] = red[0];
    }
  } else if (csel < 256){
    int h = csel - 128;
    float acc = 0.f;
    for (int j = j0; j < j0 + 64; ++j)
      acc = fmaf(Wv[(size_t)j * 256 + o], W1[(size_t)h * 384 + j], acc);
    partial[t] = acc;
    if (tch == 0) red[t] = bv[t] * W1[(size_t)h * 384 + t];
    __syncthreads();
    if (t < 64){
      float a = partial[t] + partial[t + 64] + partial[t + 128] + partial[t + 192];
      WvuS[(size_t)((o >> 2) * 128 + h) * 4 + (o & 3)] = a;
    }
    if (tch == 0){
      for (int s = 128; s > 0; s >>= 1){ if (t < s) red[t] += red[t + s]; __syncthreads(); }
      if (t == 0) bvu[h] = red[0];
    }
  } else {
    float acc = 0.f;
    for (int j = j0; j < j0 + 64; ++j)
      acc = fmaf(Wk[(size_t)j * 256 + o], bq[j], acc);
    partial[t] = acc;
    if (tch == 0) red[t] = bk[t] * bq[t];
    __syncthreads();
    if (t < 64){
      float a = partial[t] + partial[t + 64] + partial[t + 128] + partial[t + 192];
      wbq[o] = a;
    }
    if (tch == 0){
      for (int s = 128; s > 0; s >>= 1){ if (t < s) red[t] += red[t + s]; __syncthreads(); }
      if (t == 0) sbq[0] = red[0];
    }
  }
}

// ---------- k_dk: fused k_dec + k_knn, block-interleaved for CU co-residency (unchanged) ----------
__global__ __launch_bounds__(256) void k_dk(const float* __restrict__ df,
                                            const float4* __restrict__ WkqS,
                                            const float4* __restrict__ WvuS,
                                            const float* __restrict__ bkq,
                                            const float* __restrict__ bvu,
                                            const float* __restrict__ wbq,
                                            const float* __restrict__ sbq,
                                            bf16* __restrict__ Zd, bf16* __restrict__ Ud,
                                            float* __restrict__ bqK,
                                            const float* __restrict__ epos,
                                            const float4* __restrict__ posP,
                                            int* __restrict__ knnI){
  __shared__ float dpart[8][32];
  __shared__ float smin[8 * 64];
  __shared__ float tauLDS[8];
  __shared__ int   cntL[8][4];
  __shared__ float lval[8][4][64];
  __shared__ int   lidx[8][4][64];

  int g = blockIdx.x, t = threadIdx.x;
  int m = g % 5, q5 = g / 5;
  if (m == 4){
    // ================= dec path (block q5 of 1024) =================
    int g0 = q5 * 8;
    int half = __builtin_amdgcn_readfirstlane(t >> 7);
    int c = t & 127;
    const float4* W = half ? WvuS : WkqS;
    float acc[8];
    #pragma unroll
    for (int p = 0; p < 8; ++p) acc[p] = 0.f;
    for (int j4 = 0; j4 < 64; ++j4){
      float4 w = W[j4 * 128 + c];
      #pragma unroll
      for (int p = 0; p < 8; ++p){
        float4 a = ((const float4*)(df + (size_t)(g0 + p) * 256))[j4];
        acc[p] += w.x*a.x + w.y*a.y + w.z*a.z + w.w*a.w;
      }
    }
    float bias = half ? bvu[c] : bkq[c];
    bf16* dst = half ? Ud : Zd;
    #pragma unroll
    for (int p = 0; p < 8; ++p)
      dst[(size_t)(g0 + p) * 128 + c] = __float2bfloat16(acc[p] + bias);
    {
      int r = t >> 5, seg = t & 31;
      float s = 0.f;
      const float* dr = df + (size_t)(g0 + r) * 256 + seg * 8;
      const float* wq = wbq + seg * 8;
      #pragma unroll
      for (int e = 0; e < 8; ++e) s = fmaf(dr[e], wq[e], s);
      dpart[r][seg] = s;
    }
    __syncthreads();
    if (t < 8){
      float s = sbq[0];
      #pragma unroll
      for (int seg = 0; seg < 32; ++seg) s += dpart[t][seg];
      bqK[g0 + t] = s;
    }
    return;
  }

  // ================= knn path (block kb of 4096) =================
  int kb = q5 * 4 + m;
  int lane = t & 63, w = t >> 6;
  int n0 = kb * 8;
  f32x2 nex2[8], ney2[8], nez2[8];
  #pragma unroll
  for (int p = 0; p < 8; ++p){
    float nx = -epos[(n0 + p) * 3 + 0];
    float ny = -epos[(n0 + p) * 3 + 1];
    float nz = -epos[(n0 + p) * 3 + 2];
    nex2[p].x = nx; nex2[p].y = nx;
    ney2[p].x = ny; ney2[p].y = ny;
    nez2[p].x = nz; nez2[p].y = nz;
  }
  const float4* base = posP + w * 2048;   // wave's 1024 candidate-pairs = 2048 float4

  // PASS A: per-lane minima over 2 packed candidates/iter (3 pk_fma + 2 min per point)
  f32x2 vmin2[8];
  #pragma unroll
  for (int p = 0; p < 8; ++p){ vmin2[p].x = FMAXV; vmin2[p].y = FMAXV; }
  #pragma unroll 4
  for (int s = 0; s < 16; ++s){
    int q2 = (s * 64 + lane) * 2;
    float4 XY = base[q2], ZW = base[q2 + 1];
    f32x2 X = {XY.x, XY.y}, Y = {XY.z, XY.w}, Z = {ZW.x, ZW.y}, W = {ZW.z, ZW.w};
    #pragma unroll
    for (int p = 0; p < 8; ++p){
      f32x2 v2 = pk_fma(nex2[p], X, W);
      v2 = pk_fma(ney2[p], Y, v2);
      v2 = pk_fma(nez2[p], Z, v2);
      vmin2[p].x = fminf(vmin2[p].x, v2.x);
      vmin2[p].y = fminf(vmin2[p].y, v2.y);
    }
  }
  float vmin[8];
  #pragma unroll
  for (int p = 0; p < 8; ++p) vmin[p] = fminf(vmin2[p].x, vmin2[p].y);

  // full bitonic sort of 64 lane-minima, 8 point-registers at once (lanes 0..15 -> ascending top-16)
  #pragma unroll
  for (int k = 2; k <= 64; k <<= 1){
    #pragma unroll
    for (int j = k >> 1; j > 0; j >>= 1){
      bool keepmin = ((lane & j) == 0) == ((lane & k) == 0);
      #pragma unroll
      for (int p = 0; p < 8; ++p){
        float pv = __shfl_xor(vmin[p], j);
        vmin[p] = keepmin ? fminf(vmin[p], pv) : fmaxf(vmin[p], pv);
      }
    }
  }
  if (lane < 16){
    #pragma unroll
    for (int p = 0; p < 8; ++p) smin[p * 64 + w * 16 + lane] = vmin[p];
  }
  __syncthreads();

  // union 17th-smallest for points 2w, 2w+1 (interleaved).
  {
    int src = (lane & 16) ? (lane ^ 15) : lane;
    float v0 = smin[(w * 2 + 0) * 64 + src];
    float v1 = smin[(w * 2 + 1) * 64 + src];
    #pragma unroll
    for (int j = 16; j > 0; j >>= 1){
      bool keepmin = ((lane & 32) == 0) == ((lane & j) == 0);
      float p0 = __shfl_xor(v0, j); v0 = keepmin ? fminf(v0, p0) : fmaxf(v0, p0);
      float p1 = __shfl_xor(v1, j); v1 = keepmin ? fminf(v1, p1) : fmaxf(v1, p1);
    }
    #pragma unroll
    for (int j = 32; j > 0; j >>= 1){
      bool keepmin = ((lane & j) == 0);
      float p0 = __shfl_xor(v0, j); v0 = keepmin ? fminf(v0, p0) : fmaxf(v0, p0);
      float p1 = __shfl_xor(v1, j); v1 = keepmin ? fminf(v1, p1) : fmaxf(v1, p1);
    }
    if (lane == 16){ tauLDS[w * 2] = v0; tauLDS[w * 2 + 1] = v1; }
  }
  __syncthreads();
  float tau0[8];
  #pragma unroll
  for (int p = 0; p < 8; ++p) tau0[p] = tauLDS[p];

  // PASS B: ballot + prefix-popcount append into per-wave private buffers
  unsigned long long lmlt = (1ull << lane) - 1ull;
  int cnt[8] = {0,0,0,0,0,0,0,0};
  #pragma unroll 2
  for (int s = 0; s < 16; ++s){
    int q = s * 64 + lane;
    float4 XY = base[q * 2], ZW = base[q * 2 + 1];
    f32x2 X = {XY.x, XY.y}, Y = {XY.z, XY.w}, Z = {ZW.x, ZW.y}, W = {ZW.z, ZW.w};
    int cand0 = w * 2048 + q * 2;
    #pragma unroll
    for (int p = 0; p < 8; ++p){
      f32x2 v2 = pk_fma(nex2[p], X, W);
      v2 = pk_fma(ney2[p], Y, v2);
      v2 = pk_fma(nez2[p], Z, v2);
      bool h0 = v2.x <= tau0[p];
      bool h1 = v2.y <= tau0[p];
      unsigned long long m0 = __ballot(h0);
      unsigned long long m1 = __ballot(h1);
      if (m0 | m1){   // wave-uniform skip
        int base0 = cnt[p];
        int c0 = (int)__popcll(m0);
        if (h0){
          int s0 = base0 + (int)__popcll(m0 & lmlt);
          if (s0 < 64){ lval[p][w][s0] = v2.x; lidx[p][w][s0] = cand0; }
        }
        if (h1){
          int s1 = base0 + c0 + (int)__popcll(m1 & lmlt);
          if (s1 < 64){ lval[p][w][s1] = v2.y; lidx[p][w][s1] = cand0 + 1; }
        }
        cnt[p] = base0 + c0 + (int)__popcll(m1);
      }
    }
  }
  if (lane == 0){
    #pragma unroll
    for (int p = 0; p < 8; ++p) cntL[p][w] = (cnt[p] > 64) ? 64 : cnt[p];
  }
  __syncthreads();

  // finalize points 2w, 2w+1 interleaved: gather from 4 private segments, exact select-16
  {
    int p0 = w * 2, p1 = w * 2 + 1;
    int nA = n0 + p0, nB = n0 + p1;
    int cA0 = cntL[p0][0], cA1 = cntL[p0][1], cA2 = cntL[p0][2], cA3 = cntL[p0][3];
    int cB0 = cntL[p1][0], cB1 = cntL[p1][1], cB2 = cntL[p1][2], cB3 = cntL[p1][3];
    int oA1 = cA0, oA2 = oA1 + cA1, oA3 = oA2 + cA2; int totA = oA3 + cA3; if (totA > 64) totA = 64;
    int oB1 = cB0, oB2 = oB1 + cB1, oB3 = oB2 + cB2; int totB = oB3 + cB3; if (totB > 64) totB = 64;
    int segA = (lane >= oA1) + (lane >= oA2) + (lane >= oA3);
    int segB = (lane >= oB1) + (lane >= oB2) + (lane >= oB3);
    int basA = segA == 0 ? 0 : (segA == 1 ? oA1 : (segA == 2 ? oA2 : oA3));
    int basB = segB == 0 ? 0 : (segB == 1 ? oB1 : (segB == 2 ? oB2 : oB3));
    float va = (lane < totA) ? lval[p0][segA][lane - basA] : FMAXV;
    int   ia = (lane < totA) ? lidx[p0][segA][lane - basA] : 0x7fffffff;
    float vb = (lane < totB) ? lval[p1][segB][lane - basB] : FMAXV;
    int   ib = (lane < totB) ? lidx[p1][segB][lane - basB] : 0x7fffffff;

    #pragma unroll
    for (int k = 2; k <= 16; k <<= 1){
      #pragma unroll
      for (int j = k >> 1; j > 0; j >>= 1){
        bool keepmin = ((lane & k) == 0) == ((lane & j) == 0);
        { float pv = __shfl_xor(va, j); int pid = __shfl_xor(ia, j);
          bool pl = (pv < va) || (pv == va && pid < ia);
          if (keepmin ? pl : !pl){ va = pv; ia = pid; } }
        { float pv = __shfl_xor(vb, j); int pid = __shfl_xor(ib, j);
          bool pl = (pv < vb) || (pv == vb && pid < ib);
          if (keepmin ? pl : !pl){ vb = pv; ib = pid; } }
      }
    }
    { float pv = __shfl_xor(va, 16); int pid = __shfl_xor(ia, 16);
      if ((pv < va) || (pv == va && pid < ia)){ va = pv; ia = pid; } }
    { float pv = __shfl_xor(vb, 16); int pid = __shfl_xor(ib, 16);
      if ((pv < vb) || (pv == vb && pid < ib)){ vb = pv; ib = pid; } }
    #pragma unroll
    for (int j = 8; j > 0; j >>= 1){
      bool keepmin = ((lane & 32) == 0) == ((lane & j) == 0);
      { float pv = __shfl_xor(va, j); int pid = __shfl_xor(ia, j);
        bool pl = (pv < va) || (pv == va && pid < ia);
        if (keepmin ? pl : !pl){ va = pv; ia = pid; } }
      { float pv = __shfl_xor(vb, j); int pid = __shfl_xor(ib, j);
        bool pl = (pv < vb) || (pv == vb && pid < ib);
        if (keepmin ? pl : !pl){ vb = pv; ib = pid; } }
    }
    { float pv = __shfl_xor(va, 32); int pid = __shfl_xor(ia, 32);
      if ((pv < va) || (pv == va && pid < ia)){ va = pv; ia = pid; } }
    { float pv = __shfl_xor(vb, 32); int pid = __shfl_xor(ib, 32);
      if ((pv < vb) || (pv == vb && pid < ib)){ vb = pv; ib = pid; } }

    if (lane < 16){
      knnI[(size_t)nA * 16 + lane] = ia;
      knnI[(size_t)nB * 16 + lane] = ib;
    }
  }
}

// ---------- k_amlp: fused attention read-out + MLP + LN ----------
// Score phase coalesced: lane kk holds ef dims kk*8..+8; the 16-lane group walks the 16
// neighbor Zd rows contiguously producing per-lane partials qv[k2]; CORRECTED reduce-scatter
// butterfly (keep/send select by lane bit, same element index added across partner lanes)
// leaves the full score of neighbor kk in lane kk.
__global__ __launch_bounds__(256) void k_amlp(const int* __restrict__ knnI,
                                              const bf16* __restrict__ Zd,
                                              const bf16* __restrict__ Ud,
                                              const float* __restrict__ bqK,
                                              const float* __restrict__ ef,
                                              const float4* __restrict__ W1eSa,
                                              const float4* __restrict__ W1eSb,
                                              const float* __restrict__ b1,
                                              const float4* __restrict__ W2Sa,
                                              const float4* __restrict__ W2Sb,
                                              const float* __restrict__ b2,
                                              const float* __restrict__ lng, const float* __restrict__ lnb,
                                              float* __restrict__ out){
  __shared__ float haggL[16 * 128];
  __shared__ float hbuf[16 * 128];
  __shared__ float ubuf[16 * 128];
  __shared__ float stats[32];
  int t = threadIdx.x;
  int n0 = blockIdx.x * 16;
  int lane = t & 63, w = t >> 6;

  // ---- attention phase: point pp = w*4 + (lane>>4), neighbor slot kk = lane&15 ----
  {
    int kk = lane & 15;
    int pp = w * 4 + (lane >> 4);
    int n = n0 + pp;
    int ik = knnI[(size_t)n * 16 + kk];
    float bz = bqK[ik];
    // lane-local ef segment (dims kk*8 .. kk*8+7), coalesced 512B row read per group
    const float4* e4 = (const float4*)(ef + (size_t)n * 128 + kk * 8);
    float4 ea = e4[0], eb = e4[1];
    // broadcast the group's 16 neighbor indices
    int gbase = lane & 48;
    int ikk[16];
    #pragma unroll
    for (int k2 = 0; k2 < 16; ++k2) ikk[k2] = __shfl(ik, gbase | k2);
    // coalesced row reads -> per-lane partials qv[k2] = <ef_seg, Zd[ikk[k2]]_seg>
    float qv[16];
    {
      uint4 zb[8];
      #pragma unroll
      for (int k2 = 0; k2 < 8; ++k2) zb[k2] = *(const uint4*)((const u16*)Zd + (size_t)ikk[k2] * 128 + kk * 8);
      #pragma unroll
      for (int k2 = 0; k2 < 8; ++k2){
        uint4 z = zb[k2];
        float s;
        s = ea.x * asfloat(z.x << 16);
        s = fmaf(ea.y, asfloat(z.x & 0xffff0000u), s);
        s = fmaf(ea.z, asfloat(z.y << 16), s);
        s = fmaf(ea.w, asfloat(z.y & 0xffff0000u), s);
        s = fmaf(eb.x, asfloat(z.z << 16), s);
        s = fmaf(eb.y, asfloat(z.z & 0xffff0000u), s);
        s = fmaf(eb.z, asfloat(z.w << 16), s);
        s = fmaf(eb.w, asfloat(z.w & 0xffff0000u), s);
        qv[k2] = s;
      }
      #pragma unroll
      for (int k2 = 0; k2 < 8; ++k2) zb[k2] = *(const uint4*)((const u16*)Zd + (size_t)ikk[8 + k2] * 128 + kk * 8);
      #pragma unroll
      for (int k2 = 0; k2 < 8; ++k2){
        uint4 z = zb[k2];
        float s;
        s = ea.x * asfloat(z.x << 16);
        s = fmaf(ea.y, asfloat(z.x & 0xffff0000u), s);
        s = fmaf(ea.z, asfloat(z.y << 16), s);
        s = fmaf(ea.w, asfloat(z.y & 0xffff0000u), s);
        s = fmaf(eb.x, asfloat(z.z << 16), s);
        s = fmaf(eb.y, asfloat(z.z & 0xffff0000u), s);
        s = fmaf(eb.z, asfloat(z.w << 16), s);
        s = fmaf(eb.w, asfloat(z.w & 0xffff0000u), s);
        qv[8 + k2] = s;
      }
    }
    // CORRECT reduce-scatter butterfly: stage m keeps elements e with (e&m)==(lane&m),
    // adding the partner's value of the SAME element. After m=1,2,4,8 lane kk holds
    // q1 = full 128-dim score of neighbor kk.
    bool b1v = (lane & 1) != 0, b2v = (lane & 2) != 0, b4 = (lane & 4) != 0, b8 = (lane & 8) != 0;
    float q8[8];
    #pragma unroll
    for (int j = 0; j < 8; ++j){
      float keep = b1v ? qv[2*j+1] : qv[2*j];
      float send = b1v ? qv[2*j]   : qv[2*j+1];
      q8[j] = keep + __shfl_xor(send, 1);
    }
    float q4[4];
    #pragma unroll
    for (int j = 0; j < 4; ++j){
      float keep = b2v ? q8[2*j+1] : q8[2*j];
      float send = b2v ? q8[2*j]   : q8[2*j+1];
      q4[j] = keep + __shfl_xor(send, 2);
    }
    float q2[2];
    #pragma unroll
    for (int j = 0; j < 2; ++j){
      float keep = b4 ? q4[2*j+1] : q4[2*j];
      float send = b4 ? q4[2*j]   : q4[2*j+1];
      q2[j] = keep + __shfl_xor(send, 4);
    }
    float q1;
    {
      float keep = b8 ? q2[1] : q2[0];
      float send = b8 ? q2[0] : q2[1];
      q1 = keep + __shfl_xor(send, 8);
    }
    float sc = (q1 + bz) * (1.0f / 16.0f);
    float mx = sc;
    #pragma unroll
    for (int off = 1; off < 16; off <<= 1) mx = fmaxf(mx, __shfl_xor(mx, off));
    float e = __expf(sc - mx);
    float l = e;
    #pragma unroll
    for (int off = 1; off < 16; off <<= 1) l += __shfl_xor(l, off);
    float wgt = e / l;

    // agg: pre-broadcast weights, batched coalesced Ud row gathers
    float wk[16];
    #pragma unroll
    for (int k2 = 0; k2 < 16; ++k2) wk[k2] = __shfl(wgt, gbase | k2);
    float acc8[8];
    #pragma unroll
    for (int j = 0; j < 8; ++j) acc8[j] = 0.f;
    {
      uint4 ub[8];
      #pragma unroll
      for (int k2 = 0; k2 < 8; ++k2) ub[k2] = *(const uint4*)((const u16*)Ud + (size_t)ikk[k2] * 128 + kk * 8);
      #pragma unroll
      for (int k2 = 0; k2 < 8; ++k2){
        uint4 uu = ub[k2]; float wv = wk[k2];
        acc8[0] = fmaf(wv, asfloat(uu.x << 16), acc8[0]);
        acc8[1] = fmaf(wv, asfloat(uu.x & 0xffff0000u), acc8[1]);
        acc8[2] = fmaf(wv, asfloat(uu.y << 16), acc8[2]);
        acc8[3] = fmaf(wv, asfloat(uu.y & 0xffff0000u), acc8[3]);
        acc8[4] = fmaf(wv, asfloat(uu.z << 16), acc8[4]);
        acc8[5] = fmaf(wv, asfloat(uu.z & 0xffff0000u), acc8[5]);
        acc8[6] = fmaf(wv, asfloat(uu.w << 16), acc8[6]);
        acc8[7] = fmaf(wv, asfloat(uu.w & 0xffff0000u), acc8[7]);
      }
      #pragma unroll
      for (int k2 = 0; k2 < 8; ++k2) ub[k2] = *(const uint4*)((const u16*)Ud + (size_t)ikk[8 + k2] * 128 + kk * 8);
      #pragma unroll
      for (int k2 = 0; k2 < 8; ++k2){
        uint4 uu = ub[k2]; float wv = wk[8 + k2];
        acc8[0] = fmaf(wv, asfloat(uu.x << 16), acc8[0]);
        acc8[1] = fmaf(wv, asfloat(uu.x & 0xffff0000u), acc8[1]);
        acc8[2] = fmaf(wv, asfloat(uu.y << 16), acc8[2]);
        acc8[3] = fmaf(wv, asfloat(uu.y & 0xffff0000u), acc8[3]);
        acc8[4] = fmaf(wv, asfloat(uu.z << 16), acc8[4]);
        acc8[5] = fmaf(wv, asfloat(uu.z & 0xffff0000u), acc8[5]);
        acc8[6] = fmaf(wv, asfloat(uu.w << 16), acc8[6]);
        acc8[7] = fmaf(wv, asfloat(uu.w & 0xffff0000u), acc8[7]);
      }
    }
    float4* hp = (float4*)&haggL[pp * 128 + kk * 8];
    hp[0] = make_float4(acc8[0], acc8[1], acc8[2], acc8[3]);
    hp[1] = make_float4(acc8[4], acc8[5], acc8[6], acc8[7]);
  }

  // ---- MLP phase ----
  int jg = t & 63;
  int pg4 = __builtin_amdgcn_readfirstlane((t >> 6) * 4);
  int j0 = jg * 2;
  float acc[2][4];
  #pragma unroll
  for (int a = 0; a < 2; ++a)
    #pragma unroll
    for (int p = 0; p < 4; ++p) acc[a][p] = 0.f;
  #pragma unroll 4
  for (int c4 = 0; c4 < 32; ++c4){
    float4 wa = W1eSa[c4 * 64 + jg];
    float4 wb = W1eSb[c4 * 64 + jg];
    #pragma unroll
    for (int p = 0; p < 4; ++p){
      float4 x = ((const float4*)(ef + (size_t)(n0 + pg4 + p) * 128))[c4];
      acc[0][p] += wa.x*x.x + wa.y*x.y + wa.z*x.z + wa.w*x.w;
      acc[1][p] += wb.x*x.x + wb.y*x.y + wb.z*x.z + wb.w*x.w;
    }
  }
  __syncthreads();   // haggL ready
  float b1a = b1[j0], b1b = b1[j0 + 1];
  #pragma unroll
  for (int p = 0; p < 4; ++p){
    float2 hgv = *(const float2*)&haggL[(pg4 + p) * 128 + j0];
    hbuf[(pg4 + p) * 128 + j0]     = fmaxf(acc[0][p] + b1a + hgv.x, 0.f);
    hbuf[(pg4 + p) * 128 + j0 + 1] = fmaxf(acc[1][p] + b1b + hgv.y, 0.f);
  }
  __syncthreads();
  float acc2[2][4];
  #pragma unroll
  for (int a = 0; a < 2; ++a)
    #pragma unroll
    for (int p = 0; p < 4; ++p) acc2[a][p] = 0.f;
  const float4* hb4 = (const float4*)hbuf;
  #pragma unroll 4
  for (int c4 = 0; c4 < 32; ++c4){
    float4 wa = W2Sa[c4 * 64 + jg];
    float4 wb = W2Sb[c4 * 64 + jg];
    #pragma unroll
    for (int p = 0; p < 4; ++p){
      float4 x = hb4[(pg4 + p) * 32 + c4];
      acc2[0][p] += wa.x*x.x + wa.y*x.y + wa.z*x.z + wa.w*x.w;
      acc2[1][p] += wb.x*x.x + wb.y*x.y + wb.z*x.z + wb.w*x.w;
    }
  }
  float b2a = b2[j0], b2b = b2[j0 + 1];
  float u[2][4];
  #pragma unroll
  for (int p = 0; p < 4; ++p){
    u[0][p] = acc2[0][p] + b2a;
    u[1][p] = acc2[1][p] + b2b;
    ubuf[(pg4 + p) * 128 + j0]     = u[0][p];
    ubuf[(pg4 + p) * 128 + j0 + 1] = u[1][p];
  }
  __syncthreads();
  {
    int p = t >> 4, qi = t & 15;
    const float* ub = &ubuf[p * 128 + qi * 8];
    float s = 0.f, s2 = 0.f;
    #pragma unroll
    for (int e2i = 0; e2i < 8; ++e2i){ float v = ub[e2i]; s += v; s2 += v * v; }
    #pragma unroll
    for (int off = 1; off < 16; off <<= 1){ s += __shfl_xor(s, off); s2 += __shfl_xor(s2, off); }
    if (qi == 0){
      float mu = s * (1.f / 128.f);
      float var = s2 * (1.f / 128.f) - mu * mu;
      stats[p] = mu;
      stats[16 + p] = rsqrtf(fmaxf(var, 0.f) + 1e-5f);
    }
  }
  __syncthreads();
  float ga = lng[j0], gb = lng[j0 + 1];
  float ba = lnb[j0], bbv = lnb[j0 + 1];
  #pragma unroll
  for (int p = 0; p < 4; ++p){
    float mu = stats[pg4 + p], rs = stats[16 + pg4 + p];
    out[(size_t)(n0 + pg4 + p) * 128 + j0]     = (u[0][p] - mu) * rs * ga + ba;
    out[(size_t)(n0 + pg4 + p) * 128 + j0 + 1] = (u[1][p] - mu) * rs * gb + bbv;
  }
}

extern "C" void kernel_launch(void* const* d_in, const int* in_sizes, int n_in,
                              void* d_out, int out_size, void* d_ws, size_t ws_size,
                              hipStream_t stream){
  const float* df   = (const float*)d_in[0];
  const float* dpos = (const float*)d_in[1];
  const float* ef   = (const float*)d_in[2];
  const float* epos = (const float*)d_in[3];
  const int*   lab  = (const int*)d_in[4];
  const float* Wq = (const float*)d_in[5];
  const float* bq = (const float*)d_in[6];
  const float* Wk = (const float*)d_in[7];
  const float* bk = (const float*)d_in[8];
  const float* Wv = (const float*)d_in[9];
  const float* bv = (const float*)d_in[10];
  const float* W1 = (const float*)d_in[11];
  const float* b1 = (const float*)d_in[12];
  const float* W2 = (const float*)d_in[13];
  const float* b2 = (const float*)d_in[14];
  const float* lng = (const float*)d_in[15];
  const float* lnb = (const float*)d_in[16];
  float* out = (float*)d_out;

  // workspace layout (~13.2 MB)
  char* wsb = (char*)d_ws;
  float4* posP  = (float4*)(wsb);                    // 128 KB
  bf16*   Zd    = (bf16*)(wsb + 131072);             // 2 MB
  bf16*   Ud    = (bf16*)(wsb + 2228224);            // 2 MB
  float*  bqK   = (float*)(wsb + 4325376);           // 32 KB
  int*    knnI  = (int*)(wsb + 4358144);             // 2 MB (NF*16*4)
  float4* W1eSa = (float4*)(wsb + 12746752);         // 32 KB
  float4* W1eSb = (float4*)(wsb + 12779520);         // 32 KB
  float4* W2Sa  = (float4*)(wsb + 12812288);         // 32 KB
  float4* W2Sb  = (float4*)(wsb + 12845056);         // 32 KB
  float*  WkqS  = (float*)(wsb + 12877824);          // 128 KB
  float*  WvuS  = (float*)(wsb + 13008896);          // 128 KB
  float*  bkq   = (float*)(wsb + 13139968);          // 512 B
  float*  bvu   = (float*)(wsb + 13140480);          // 512 B
  float*  wbq   = (float*)(wsb + 13140992);          // 1 KB
  float*  sbq   = (float*)(wsb + 13142016);          // 4 B

  k_pw   <<<1220, 256, 0, stream>>>(dpos, W1, W2, posP, W1eSa, W1eSb, W2Sa, W2Sb,
                                    Wk, Wv, Wq, bk, bv, bq, WkqS, WvuS, bkq, bvu, wbq, sbq,
                                    epos, lab, out);
  k_dk   <<<5120, 256, 0, stream>>>(df, (const float4*)WkqS, (const float4*)WvuS, bkq, bvu, wbq, sbq,
                                    Zd, Ud, bqK, epos, posP, knnI);
  k_amlp <<<NF / 16, 256, 0, stream>>>(knnI, Zd, Ud, bqK, ef, W1eSa, W1eSb, b1, W2Sa, W2Sb, b2, lng, lnb, out);
  (void)in_sizes; (void)n_in; (void)out_size; (void)ws_size;
}